// Round 2
// baseline (458.869 us; speedup 1.0000x reference)
//
#include <hip/hip_runtime.h>

#define ROWS 8192
#define LW 96
#define HW 8
#define DM 768
#define DI 3072

typedef __bf16 bf16x8 __attribute__((ext_vector_type(8)));
typedef float f32x4 __attribute__((ext_vector_type(4)));

__device__ __forceinline__ unsigned short bfbits(__bf16 b) {
    return __builtin_bit_cast(unsigned short, b);
}
__device__ __forceinline__ void decomp(float v, unsigned short& hi, unsigned short& lo) {
    __bf16 hb = (__bf16)v;
    float hf = (float)hb;
    __bf16 lb = (__bf16)(v - hf);
    hi = bfbits(hb); lo = bfbits(lb);
}
__device__ __forceinline__ void gload_lds16(const void* g, void* l) {
    __builtin_amdgcn_global_load_lds((const __attribute__((address_space(1))) unsigned int*)g,
                                     (__attribute__((address_space(3))) unsigned int*)l, 16, 0, 0);
}

// ---------------- Kernel 0: weight transpose + bf16 hi/lo decompose ----------------
// W[K][N] fp32 -> Th/Tl[N][K] bf16 bits
__global__ __launch_bounds__(256) void k_wprep(
    const float* __restrict__ W, unsigned short* __restrict__ Th,
    unsigned short* __restrict__ Tl, int K, int N)
{
    __shared__ float tile[32][33];
    const int tx = threadIdx.x & 31, ty = threadIdx.x >> 5;  // 32x8
    const int k0 = blockIdx.y * 32, n0 = blockIdx.x * 32;
#pragma unroll
    for (int i = 0; i < 32; i += 8)
        tile[ty + i][tx] = W[(size_t)(k0 + ty + i) * N + n0 + tx];
    __syncthreads();
#pragma unroll
    for (int i = 0; i < 32; i += 8) {
        int n = n0 + ty + i, k = k0 + tx;
        unsigned short h, l;
        decomp(tile[tx][ty + i], h, l);
        Th[(size_t)n * K + k] = h;
        Tl[(size_t)n * K + k] = l;
    }
}

// ---------------- Kernel 1: attention (outer-product simplification) + residual + LN1 ----------------
// scores[j] = q[j] * (sum_k k[k]*mask[j,k]) / max(||q||*||k||, 1e-12)
__global__ __launch_bounds__(256) void k_attn_ln1(
    const float* __restrict__ inp, const float* __restrict__ mask,
    const float* __restrict__ wq, const float* __restrict__ bq,
    const float* __restrict__ wk, const float* __restrict__ bk,
    const float* __restrict__ wv, const float* __restrict__ bv,
    const float* __restrict__ g1, const float* __restrict__ be1,
    float* __restrict__ xout, unsigned short* __restrict__ xh,
    unsigned short* __restrict__ xl)
{
    const int t = threadIdx.x;
    const int row = blockIdx.x;
    __shared__ float sr[DM];
    __shared__ float sq[LW], sk[LW], sv[LW], sres[LW];
    __shared__ float red[256];

    const float* rp = inp + (size_t)row * DM;
    for (int i = t; i < DM / 4; i += 256)
        ((float4*)sr)[i] = ((const float4*)rp)[i];
    __syncthreads();

    if (t < LW) {
        const float* hp = sr + t * HW;
        float aq = 0.f, ak = 0.f, av = 0.f;
#pragma unroll
        for (int i = 0; i < HW; i++) {
            float x = hp[i];
            aq += x * wq[i]; ak += x * wk[i]; av += x * wv[i];
        }
        sq[t] = aq + bq[0]; sk[t] = ak + bk[0]; sv[t] = av + bv[0];
    }
    __syncthreads();

    float pq = (t < LW) ? sq[t] * sq[t] : 0.f;
    float pk = (t < LW) ? sk[t] * sk[t] : 0.f;
    red[t] = pq; __syncthreads();
    for (int s = 128; s > 0; s >>= 1) { if (t < s) red[t] += red[t + s]; __syncthreads(); }
    float nq2 = red[0]; __syncthreads();
    red[t] = pk; __syncthreads();
    for (int s = 128; s > 0; s >>= 1) { if (t < s) red[t] += red[t + s]; __syncthreads(); }
    float nk2 = red[0]; __syncthreads();
    float inv = 1.f / fmaxf(sqrtf(nq2) * sqrtf(nk2), 1e-12f);

    float sc = -1e30f;
    if (t < LW) {
        float acc = 0.f;
        const float* mr = mask + t * LW;
        for (int kk = 0; kk < LW; kk++) acc += sk[kk] * mr[kk];
        sc = sq[t] * acc * inv;
    }
    red[t] = sc; __syncthreads();
    for (int s = 128; s > 0; s >>= 1) { if (t < s) red[t] = fmaxf(red[t], red[t + s]); __syncthreads(); }
    float mx = red[0]; __syncthreads();
    float e = (t < LW) ? __expf(sc - mx) : 0.f;
    red[t] = e; __syncthreads();
    for (int s = 128; s > 0; s >>= 1) { if (t < s) red[t] += red[t + s]; __syncthreads(); }
    float se = red[0]; __syncthreads();
    if (t < LW) sres[t] = (e / se) * sv[t];
    __syncthreads();

    float xs[3]; float sum = 0.f;
#pragma unroll
    for (int i = 0; i < 3; i++) {
        int d = t + i * 256;
        float xv = sr[d] + sres[d >> 3];
        xs[i] = xv; sum += xv;
    }
    red[t] = sum; __syncthreads();
    for (int s = 128; s > 0; s >>= 1) { if (t < s) red[t] += red[t + s]; __syncthreads(); }
    float mean = red[0] * (1.f / DM); __syncthreads();
    float vs = 0.f;
#pragma unroll
    for (int i = 0; i < 3; i++) { float dd = xs[i] - mean; vs += dd * dd; }
    red[t] = vs; __syncthreads();
    for (int s = 128; s > 0; s >>= 1) { if (t < s) red[t] += red[t + s]; __syncthreads(); }
    float rstd = rsqrtf(red[0] * (1.f / DM) + 1e-6f);

    float* xo = xout + (size_t)row * DM;
    unsigned short* xho = xh + (size_t)row * DM;
    unsigned short* xlo = xl + (size_t)row * DM;
#pragma unroll
    for (int i = 0; i < 3; i++) {
        int d = t + i * 256;
        float v = (xs[i] - mean) * rstd * g1[d] + be1[d];
        xo[d] = v;
        unsigned short h, l;
        decomp(v, h, l);
        xho[d] = h; xlo[d] = l;
    }
}

// ---------------- split-bf16 MFMA GEMM ----------------
// C = op(A@B + bias [+ res]) with A (M x K) as hi/lo bf16 row-major,
// B pre-transposed (N x K) hi/lo bf16 row-major. 128x128 tile, BK=32,
// 256 threads = 4 waves (2x2), each wave 64x64 = 4x4 frags of 16x16x32.
// LDS linear (slot s = 16B), swizzle c' = c ^ ((r>>1)&3) applied at the
// GLOBAL source (m173) and at the ds_read -> 2-way bank alias (free).
template<int RELU, int HAS_RES, int OUT_F32, int OUT_BF16>
__global__ __launch_bounds__(256) void k_gemm_mfma(
    const unsigned short* __restrict__ Ah, const unsigned short* __restrict__ Al,
    const unsigned short* __restrict__ Bh, const unsigned short* __restrict__ Bl,
    const float* __restrict__ bias, const float* __restrict__ res,
    float* __restrict__ Cf, unsigned short* __restrict__ Ch,
    unsigned short* __restrict__ Cl, int M, int N, int K)
{
    __shared__ unsigned short sAh[4096], sAl[4096], sBh[4096], sBl[4096]; // 8 KB each

    const int t = threadIdx.x;
    const int lane = t & 63, w = t >> 6;
    const int wm = w >> 1, wn = w & 1;
    const int bn = blockIdx.x, bm = blockIdx.y;

    f32x4 acc[4][4];
#pragma unroll
    for (int i = 0; i < 4; i++)
#pragma unroll
        for (int j = 0; j < 4; j++) acc[i][j] = (f32x4)0.f;

    // staging: slot s = j*256 + t ; r = s>>2 ; chunk-in-lds c' = s&3 ;
    // chunk-in-data c = c' ^ ((r>>1)&3)
    const int r0 = t >> 2,         c0 = (t & 3) ^ ((r0 >> 1) & 3);
    const int r1 = (256 + t) >> 2, c1 = ((256 + t) & 3) ^ ((r1 >> 1) & 3);
    const size_t aRow0 = (size_t)(bm * 128 + r0) * K + c0 * 8;
    const size_t aRow1 = (size_t)(bm * 128 + r1) * K + c1 * 8;
    const size_t bRow0 = (size_t)(bn * 128 + r0) * K + c0 * 8;
    const size_t bRow1 = (size_t)(bn * 128 + r1) * K + c1 * 8;
    const int ldsOff0 = w * 512;          // ushort units (wave-uniform)
    const int ldsOff1 = 2048 + w * 512;

    // frag-read addressing
    const int fr = lane & 15, fc = lane >> 4;
    const int csw = (fc ^ ((fr >> 1) & 3)) * 8;   // swizzled chunk offset (ushorts)

    for (int kt = 0; kt < K; kt += 32) {
        gload_lds16(Ah + aRow0 + kt, sAh + ldsOff0);
        gload_lds16(Ah + aRow1 + kt, sAh + ldsOff1);
        gload_lds16(Al + aRow0 + kt, sAl + ldsOff0);
        gload_lds16(Al + aRow1 + kt, sAl + ldsOff1);
        gload_lds16(Bh + bRow0 + kt, sBh + ldsOff0);
        gload_lds16(Bh + bRow1 + kt, sBh + ldsOff1);
        gload_lds16(Bl + bRow0 + kt, sBl + ldsOff0);
        gload_lds16(Bl + bRow1 + kt, sBl + ldsOff1);
        __syncthreads();

        bf16x8 ah[4], al[4];
#pragma unroll
        for (int i = 0; i < 4; i++) {
            int idx = (wm * 64 + i * 16 + fr) * 32 + csw;
            ah[i] = *(const bf16x8*)&sAh[idx];
            al[i] = *(const bf16x8*)&sAl[idx];
        }
#pragma unroll
        for (int j = 0; j < 4; j++) {
            int idx = (wn * 64 + j * 16 + fr) * 32 + csw;
            bf16x8 bh = *(const bf16x8*)&sBh[idx];
            bf16x8 bl = *(const bf16x8*)&sBl[idx];
#pragma unroll
            for (int i = 0; i < 4; i++) {
                acc[i][j] = __builtin_amdgcn_mfma_f32_16x16x32_bf16(ah[i], bh, acc[i][j], 0, 0, 0);
                acc[i][j] = __builtin_amdgcn_mfma_f32_16x16x32_bf16(al[i], bh, acc[i][j], 0, 0, 0);
                acc[i][j] = __builtin_amdgcn_mfma_f32_16x16x32_bf16(ah[i], bl, acc[i][j], 0, 0, 0);
            }
        }
        __syncthreads();
    }

    // epilogue: C/D layout col = lane&15, row = (lane>>4)*4 + reg  [m89 verified]
#pragma unroll
    for (int i = 0; i < 4; i++) {
        int rowb = bm * 128 + wm * 64 + i * 16 + (lane >> 4) * 4;
#pragma unroll
        for (int j = 0; j < 4; j++) {
            int col = bn * 128 + wn * 64 + j * 16 + (lane & 15);
            float bb = bias[col];
#pragma unroll
            for (int rg = 0; rg < 4; rg++) {
                size_t off = (size_t)(rowb + rg) * N + col;
                float v = acc[i][j][rg] + bb;
                if (HAS_RES) v += res[off];
                if (RELU) v = fmaxf(v, 0.f);
                if (OUT_F32) Cf[off] = v;
                if (OUT_BF16) {
                    unsigned short h, l;
                    decomp(v, h, l);
                    Ch[off] = h; Cl[off] = l;
                }
            }
        }
    }
}

// ---------------- Kernel 4: LN2 ----------------
__global__ __launch_bounds__(256) void k_ln2(
    const float* __restrict__ X, const float* __restrict__ g, const float* __restrict__ b,
    float* __restrict__ out)
{
    const int t = threadIdx.x;
    const int row = blockIdx.x;
    __shared__ float red[256];
    const float* xp = X + (size_t)row * DM;
    float xs[3]; float sum = 0.f;
#pragma unroll
    for (int i = 0; i < 3; i++) { xs[i] = xp[t + i * 256]; sum += xs[i]; }
    red[t] = sum; __syncthreads();
    for (int s = 128; s > 0; s >>= 1) { if (t < s) red[t] += red[t + s]; __syncthreads(); }
    float mean = red[0] * (1.f / DM); __syncthreads();
    float vs = 0.f;
#pragma unroll
    for (int i = 0; i < 3; i++) { float dd = xs[i] - mean; vs += dd * dd; }
    red[t] = vs; __syncthreads();
    for (int s = 128; s > 0; s >>= 1) { if (t < s) red[t] += red[t + s]; __syncthreads(); }
    float rstd = rsqrtf(red[0] * (1.f / DM) + 1e-6f);
    float* op = out + (size_t)row * DM;
#pragma unroll
    for (int i = 0; i < 3; i++) { int d = t + i * 256; op[d] = (xs[i] - mean) * rstd * g[d] + b[d]; }
}

extern "C" void kernel_launch(void* const* d_in, const int* in_sizes, int n_in,
                              void* d_out, int out_size, void* d_ws, size_t ws_size,
                              hipStream_t stream) {
    const float* enc  = (const float*)d_in[0];
    const float* mask = (const float*)d_in[1];
    const float* wq = (const float*)d_in[2];  const float* bq = (const float*)d_in[3];
    const float* wk = (const float*)d_in[4];  const float* bk = (const float*)d_in[5];
    const float* wv = (const float*)d_in[6];  const float* bv = (const float*)d_in[7];
    const float* g1 = (const float*)d_in[8];  const float* be1 = (const float*)d_in[9];
    const float* w1 = (const float*)d_in[10]; const float* b1  = (const float*)d_in[11];
    const float* w2 = (const float*)d_in[12]; const float* b2  = (const float*)d_in[13];
    const float* g2 = (const float*)d_in[14]; const float* be2 = (const float*)d_in[15];
    float* out = (float*)d_out;

    // workspace layout
    char* p = (char*)d_ws;
    float* x  = (float*)p;                 p += (size_t)ROWS * DM * 4;   // 25.2 MB
    float* y  = (float*)p;                 p += (size_t)ROWS * DM * 4;   // 25.2 MB
    unsigned short* xh = (unsigned short*)p; p += (size_t)ROWS * DM * 2; // 12.6 MB
    unsigned short* xl = (unsigned short*)p; p += (size_t)ROWS * DM * 2;
    unsigned short* hh = (unsigned short*)p; p += (size_t)ROWS * DI * 2; // 50.3 MB
    unsigned short* hl = (unsigned short*)p; p += (size_t)ROWS * DI * 2;
    unsigned short* w1h = (unsigned short*)p; p += (size_t)DM * DI * 2;  // 4.7 MB
    unsigned short* w1l = (unsigned short*)p; p += (size_t)DM * DI * 2;
    unsigned short* w2h = (unsigned short*)p; p += (size_t)DM * DI * 2;
    unsigned short* w2l = (unsigned short*)p; p += (size_t)DM * DI * 2;

    // weight prep: w1 (DM x DI) -> w1t (DI x DM) hi/lo ; w2 (DI x DM) -> w2t (DM x DI)
    k_wprep<<<dim3(DI / 32, DM / 32), 256, 0, stream>>>(w1, w1h, w1l, DM, DI);
    k_wprep<<<dim3(DM / 32, DI / 32), 256, 0, stream>>>(w2, w2h, w2l, DI, DM);

    k_attn_ln1<<<ROWS, 256, 0, stream>>>(enc, mask, wq, bq, wk, bk, wv, bv, g1, be1,
                                         x, xh, xl);

    // GEMM1: h = relu(x @ w1 + b1) -> bf16 hi/lo   (M=8192, N=3072, K=768)
    k_gemm_mfma<1, 0, 0, 1><<<dim3(DI / 128, ROWS / 128), 256, 0, stream>>>(
        xh, xl, w1h, w1l, b1, nullptr, nullptr, hh, hl, ROWS, DI, DM);

    // GEMM2: y = h @ w2 + b2 + x -> fp32           (M=8192, N=768, K=3072)
    k_gemm_mfma<0, 1, 1, 0><<<dim3(DM / 128, ROWS / 128), 256, 0, stream>>>(
        hh, hl, w2h, w2l, b2, x, y, nullptr, nullptr, ROWS, DM, DI);

    k_ln2<<<ROWS, 256, 0, stream>>>(y, g2, be2, out);
}

// Round 4
// 454.458 us; speedup vs baseline: 1.0097x; 1.0097x over previous
//
#include <hip/hip_runtime.h>

#define ROWS 8192
#define LW 96
#define HW 8
#define DM 768
#define DI 3072

typedef __bf16 bf16x8 __attribute__((ext_vector_type(8)));
typedef float f32x4 __attribute__((ext_vector_type(4)));
typedef unsigned short u16;

__device__ __forceinline__ u16 bfbits(__bf16 b) {
    return __builtin_bit_cast(u16, b);
}
__device__ __forceinline__ void decomp(float v, u16& hi, u16& lo) {
    __bf16 hb = (__bf16)v;
    float hf = (float)hb;
    __bf16 lb = (__bf16)(v - hf);
    hi = bfbits(hb); lo = bfbits(lb);
}
__device__ __forceinline__ void gload16(const void* g, void* l) {
    __builtin_amdgcn_global_load_lds((const __attribute__((address_space(1))) unsigned int*)g,
                                     (__attribute__((address_space(3))) unsigned int*)l, 16, 0, 0);
}

// ---------------- Kernel 0: weight transpose + bf16 hi/lo decompose ----------------
__global__ __launch_bounds__(256) void k_wprep(
    const float* __restrict__ W, u16* __restrict__ Th,
    u16* __restrict__ Tl, int K, int N)
{
    __shared__ float tile[32][33];
    const int tx = threadIdx.x & 31, ty = threadIdx.x >> 5;
    const int k0 = blockIdx.y * 32, n0 = blockIdx.x * 32;
#pragma unroll
    for (int i = 0; i < 32; i += 8)
        tile[ty + i][tx] = W[(size_t)(k0 + ty + i) * N + n0 + tx];
    __syncthreads();
#pragma unroll
    for (int i = 0; i < 32; i += 8) {
        int n = n0 + ty + i, k = k0 + tx;
        u16 h, l;
        decomp(tile[tx][ty + i], h, l);
        Th[(size_t)n * K + k] = h;
        Tl[(size_t)n * K + k] = l;
    }
}

// ---------------- Kernel 1: attention + residual + LN1 ----------------
__global__ __launch_bounds__(256) void k_attn_ln1(
    const float* __restrict__ inp, const float* __restrict__ mask,
    const float* __restrict__ wq, const float* __restrict__ bq,
    const float* __restrict__ wk, const float* __restrict__ bk,
    const float* __restrict__ wv, const float* __restrict__ bv,
    const float* __restrict__ g1, const float* __restrict__ be1,
    float* __restrict__ xout, u16* __restrict__ xh, u16* __restrict__ xl)
{
    const int t = threadIdx.x;
    const int row = blockIdx.x;
    __shared__ float sr[DM];
    __shared__ float sq[LW], sk[LW], sv[LW], sres[LW];
    __shared__ float red[256];

    const float* rp = inp + (size_t)row * DM;
    for (int i = t; i < DM / 4; i += 256)
        ((float4*)sr)[i] = ((const float4*)rp)[i];
    __syncthreads();

    if (t < LW) {
        const float* hp = sr + t * HW;
        float aq = 0.f, ak = 0.f, av = 0.f;
#pragma unroll
        for (int i = 0; i < HW; i++) {
            float x = hp[i];
            aq += x * wq[i]; ak += x * wk[i]; av += x * wv[i];
        }
        sq[t] = aq + bq[0]; sk[t] = ak + bk[0]; sv[t] = av + bv[0];
    }
    __syncthreads();

    float pq = (t < LW) ? sq[t] * sq[t] : 0.f;
    float pk = (t < LW) ? sk[t] * sk[t] : 0.f;
    red[t] = pq; __syncthreads();
    for (int s = 128; s > 0; s >>= 1) { if (t < s) red[t] += red[t + s]; __syncthreads(); }
    float nq2 = red[0]; __syncthreads();
    red[t] = pk; __syncthreads();
    for (int s = 128; s > 0; s >>= 1) { if (t < s) red[t] += red[t + s]; __syncthreads(); }
    float nk2 = red[0]; __syncthreads();
    float inv = 1.f / fmaxf(sqrtf(nq2) * sqrtf(nk2), 1e-12f);

    float sc = -1e30f;
    if (t < LW) {
        float acc = 0.f;
        const float* mr = mask + t * LW;
        for (int kk = 0; kk < LW; kk++) acc += sk[kk] * mr[kk];
        sc = sq[t] * acc * inv;
    }
    red[t] = sc; __syncthreads();
    for (int s = 128; s > 0; s >>= 1) { if (t < s) red[t] = fmaxf(red[t], red[t + s]); __syncthreads(); }
    float mx = red[0]; __syncthreads();
    float e = (t < LW) ? __expf(sc - mx) : 0.f;
    red[t] = e; __syncthreads();
    for (int s = 128; s > 0; s >>= 1) { if (t < s) red[t] += red[t + s]; __syncthreads(); }
    float se = red[0]; __syncthreads();
    if (t < LW) sres[t] = (e / se) * sv[t];
    __syncthreads();

    float xs[3]; float sum = 0.f;
#pragma unroll
    for (int i = 0; i < 3; i++) {
        int d = t + i * 256;
        float xv = sr[d] + sres[d >> 3];
        xs[i] = xv; sum += xv;
    }
    red[t] = sum; __syncthreads();
    for (int s = 128; s > 0; s >>= 1) { if (t < s) red[t] += red[t + s]; __syncthreads(); }
    float mean = red[0] * (1.f / DM); __syncthreads();
    float vs = 0.f;
#pragma unroll
    for (int i = 0; i < 3; i++) { float dd = xs[i] - mean; vs += dd * dd; }
    red[t] = vs; __syncthreads();
    for (int s = 128; s > 0; s >>= 1) { if (t < s) red[t] += red[t + s]; __syncthreads(); }
    float rstd = rsqrtf(red[0] * (1.f / DM) + 1e-6f);

    float* xo = xout + (size_t)row * DM;
    u16* xho = xh + (size_t)row * DM;
    u16* xlo = xl + (size_t)row * DM;
#pragma unroll
    for (int i = 0; i < 3; i++) {
        int d = t + i * 256;
        float v = (xs[i] - mean) * rstd * g1[d] + be1[d];
        xo[d] = v;
        u16 h, l;
        decomp(v, h, l);
        xho[d] = h; xlo[d] = l;
    }
}

// ---------------- 8-wave split-bf16 MFMA GEMM, 256x128 tile, BK=32 ----------------
// Triple-buffered LDS ring (3 x 48KB), counted vmcnt(6), prefetch distance 2,
// one barrier per K-tile, setprio around MFMA clusters, XCD-swizzled blocks.
// SYNC ORDER (race fix vs r3): own vmcnt wait BEFORE s_barrier, so the barrier
// certifies ALL waves' tile-tt loads have landed before any cross-wave ds_read.
template<int SPLITK, int RELU, int OUT_MODE>
__global__ __launch_bounds__(512, 2) void k_gemm8(
    const u16* __restrict__ Ah, const u16* __restrict__ Al,
    const u16* __restrict__ Bh, const u16* __restrict__ Bl,
    const float* __restrict__ bias, float* __restrict__ Cf,
    u16* __restrict__ Ch, u16* __restrict__ Cl,
    int M, int N, int K)
{
    // per-buffer ushort offsets: Ah [0,8192) Al [8192,16384) Bh [16384,20480) Bl [20480,24576)
    __shared__ u16 S[3 * 24576];   // 144 KB

    const int t = threadIdx.x;
    const int lane = t & 63, w = t >> 6;
    const int wm = w >> 1, wn = w & 1;          // 4 M-waves x 2 N-waves
    const int fr = lane & 15, fq = lane >> 4;

    // bijective XCD swizzle on the flat block index (grid size % 8 == 0)
    const int gn = gridDim.x, gm = gridDim.y;
    int L = blockIdx.x + gn * (blockIdx.y + gm * blockIdx.z);
    const int nb = gn * gm * SPLITK;
    int sID = ((nb & 7) == 0) ? ((L & 7) * (nb >> 3) + (L >> 3)) : L;
    const int bz = sID / (gn * gm);
    const int r2 = sID - bz * (gn * gm);
    const int bm = r2 / gn;
    const int bn = r2 - bm * gn;

    const int KS = K / SPLITK;
    const int NT = KS / 32;
    const int kb = bz * KS;

    // staging addresses (slot s=t; r=t>>2, chunk-in-data c=(t&3)^((r>>1)&3));
    // row offset 128 keeps (r>>1)&3 unchanged, so same c for both A issues.
    const int r0 = t >> 2;                       // 0..127
    const int c0 = (t & 3) ^ ((r0 >> 1) & 3);
    const size_t aoff  = (size_t)(bm * 256 + r0) * K + kb + c0 * 8;
    const size_t aoff2 = aoff + (size_t)128 * K;
    const size_t boff  = (size_t)(bn * 128 + r0) * K + kb + c0 * 8;
    const int w512 = w * 512;                    // wave's ushort offset inside one issue

    f32x4 acc[4][4];
#pragma unroll
    for (int i = 0; i < 4; i++)
#pragma unroll
        for (int j = 0; j < 4; j++) acc[i][j] = (f32x4)0.f;

    // frag-read LDS indices (ushort units), loop-invariant
    int ai[4], bi[4];
#pragma unroll
    for (int i = 0; i < 4; i++) { int rA = wm * 64 + i * 16 + fr; ai[i] = rA * 32 + (fq ^ ((rA >> 1) & 3)) * 8; }
#pragma unroll
    for (int j = 0; j < 4; j++) { int rB = wn * 64 + j * 16 + fr; bi[j] = rB * 32 + (fq ^ ((rB >> 1) & 3)) * 8; }

#define STAGE(tile, bb)                                                  \
    { u16* Lb = S + (bb) * 24576 + w512;                                 \
      const size_t kk = (size_t)(tile) * 32;                             \
      gload16(Ah + aoff  + kk, Lb + 0);                                  \
      gload16(Ah + aoff2 + kk, Lb + 4096);                               \
      gload16(Al + aoff  + kk, Lb + 8192);                               \
      gload16(Al + aoff2 + kk, Lb + 12288);                              \
      gload16(Bh + boff  + kk, Lb + 16384);                              \
      gload16(Bl + boff  + kk, Lb + 20480); }

    STAGE(0, 0);
    STAGE(1, 1);

    for (int tt = 0; tt < NT; ++tt) {
        // wait own tile-tt loads landed, THEN barrier => all waves' tile-tt landed
        if (tt + 1 < NT) { asm volatile("s_waitcnt vmcnt(6)" ::: "memory"); }
        else             { asm volatile("s_waitcnt vmcnt(0)" ::: "memory"); }
        __builtin_amdgcn_s_barrier();
        // buf[(tt+2)%3] == buf[(tt-1)%3]: all waves finished reading tile tt-1
        // before their barrier entry, so overwrite is safe.
        if (tt + 2 < NT) STAGE(tt + 2, (tt + 2) % 3);

        const u16* Lp = S + (tt % 3) * 24576;
        bf16x8 bh[4], bl[4];
#pragma unroll
        for (int j = 0; j < 4; j++) {
            bh[j] = *(const bf16x8*)&Lp[16384 + bi[j]];
            bl[j] = *(const bf16x8*)&Lp[20480 + bi[j]];
        }
#pragma unroll
        for (int mh = 0; mh < 2; mh++) {
            bf16x8 ah[2], al[2];
#pragma unroll
            for (int i = 0; i < 2; i++) {
                ah[i] = *(const bf16x8*)&Lp[ai[mh * 2 + i]];
                al[i] = *(const bf16x8*)&Lp[8192 + ai[mh * 2 + i]];
            }
            __builtin_amdgcn_s_setprio(1);
#pragma unroll
            for (int j = 0; j < 4; j++)
#pragma unroll
                for (int i = 0; i < 2; i++) {
                    const int ii = mh * 2 + i;
                    acc[ii][j] = __builtin_amdgcn_mfma_f32_16x16x32_bf16(ah[i], bh[j], acc[ii][j], 0, 0, 0);
                    acc[ii][j] = __builtin_amdgcn_mfma_f32_16x16x32_bf16(al[i], bh[j], acc[ii][j], 0, 0, 0);
                    acc[ii][j] = __builtin_amdgcn_mfma_f32_16x16x32_bf16(ah[i], bl[j], acc[ii][j], 0, 0, 0);
                }
            __builtin_amdgcn_s_setprio(0);
        }
    }
#undef STAGE

    // epilogue: C/D frag layout col = lane&15, row = (lane>>4)*4 + reg
#pragma unroll
    for (int i = 0; i < 4; i++) {
        const int row = bm * 256 + wm * 64 + i * 16 + fq * 4;
#pragma unroll
        for (int j = 0; j < 4; j++) {
            const int col = bn * 128 + wn * 64 + j * 16 + fr;
            if (OUT_MODE == 0) {
                const float bb = bias[col];
#pragma unroll
                for (int rg = 0; rg < 4; rg++) {
                    size_t off = (size_t)(row + rg) * N + col;
                    float v = acc[i][j][rg] + bb;
                    if (RELU) v = fmaxf(v, 0.f);
                    u16 h, l;
                    decomp(v, h, l);
                    Ch[off] = h; Cl[off] = l;
                }
            } else {
#pragma unroll
                for (int rg = 0; rg < 4; rg++) {
                    size_t off = (size_t)(row + rg) * N + col;
                    atomicAdd(&Cf[off], acc[i][j][rg]);
                }
            }
        }
    }
}

// ---------------- y init for GEMM2 atomic accumulation: y = x + b2 ----------------
__global__ __launch_bounds__(256) void k_yinit(
    const float* __restrict__ x, const float* __restrict__ b2, float* __restrict__ y)
{
    const int i = blockIdx.x * 256 + threadIdx.x;   // float4 index
    const int col = (i % (DM / 4)) * 4;
    float4 xv = ((const float4*)x)[i];
    float4 bv = *(const float4*)&b2[col];
    xv.x += bv.x; xv.y += bv.y; xv.z += bv.z; xv.w += bv.w;
    ((float4*)y)[i] = xv;
}

// ---------------- LN2 ----------------
__global__ __launch_bounds__(256) void k_ln2(
    const float* __restrict__ X, const float* __restrict__ g, const float* __restrict__ b,
    float* __restrict__ out)
{
    const int t = threadIdx.x;
    const int row = blockIdx.x;
    __shared__ float red[256];
    const float* xp = X + (size_t)row * DM;
    float xs[3]; float sum = 0.f;
#pragma unroll
    for (int i = 0; i < 3; i++) { xs[i] = xp[t + i * 256]; sum += xs[i]; }
    red[t] = sum; __syncthreads();
    for (int s = 128; s > 0; s >>= 1) { if (t < s) red[t] += red[t + s]; __syncthreads(); }
    float mean = red[0] * (1.f / DM); __syncthreads();
    float vs = 0.f;
#pragma unroll
    for (int i = 0; i < 3; i++) { float dd = xs[i] - mean; vs += dd * dd; }
    red[t] = vs; __syncthreads();
    for (int s = 128; s > 0; s >>= 1) { if (t < s) red[t] += red[t + s]; __syncthreads(); }
    float rstd = rsqrtf(red[0] * (1.f / DM) + 1e-6f);
    float* op = out + (size_t)row * DM;
#pragma unroll
    for (int i = 0; i < 3; i++) { int d = t + i * 256; op[d] = (xs[i] - mean) * rstd * g[d] + b[d]; }
}

extern "C" void kernel_launch(void* const* d_in, const int* in_sizes, int n_in,
                              void* d_out, int out_size, void* d_ws, size_t ws_size,
                              hipStream_t stream) {
    const float* enc  = (const float*)d_in[0];
    const float* mask = (const float*)d_in[1];
    const float* wq = (const float*)d_in[2];  const float* bq = (const float*)d_in[3];
    const float* wk = (const float*)d_in[4];  const float* bk = (const float*)d_in[5];
    const float* wv = (const float*)d_in[6];  const float* bv = (const float*)d_in[7];
    const float* g1 = (const float*)d_in[8];  const float* be1 = (const float*)d_in[9];
    const float* w1 = (const float*)d_in[10]; const float* b1  = (const float*)d_in[11];
    const float* w2 = (const float*)d_in[12]; const float* b2  = (const float*)d_in[13];
    const float* g2 = (const float*)d_in[14]; const float* be2 = (const float*)d_in[15];
    float* out = (float*)d_out;

    // workspace layout (194 MB)
    char* p = (char*)d_ws;
    float* x  = (float*)p;                 p += (size_t)ROWS * DM * 4;   // 25.2 MB
    float* y  = (float*)p;                 p += (size_t)ROWS * DM * 4;   // 25.2 MB
    u16* xh = (u16*)p; p += (size_t)ROWS * DM * 2;                       // 12.6 MB
    u16* xl = (u16*)p; p += (size_t)ROWS * DM * 2;
    u16* hh = (u16*)p; p += (size_t)ROWS * DI * 2;                       // 50.3 MB
    u16* hl = (u16*)p; p += (size_t)ROWS * DI * 2;
    u16* w1h = (u16*)p; p += (size_t)DM * DI * 2;                        // 4.7 MB
    u16* w1l = (u16*)p; p += (size_t)DM * DI * 2;
    u16* w2h = (u16*)p; p += (size_t)DM * DI * 2;
    u16* w2l = (u16*)p; p += (size_t)DM * DI * 2;

    k_wprep<<<dim3(DI / 32, DM / 32), 256, 0, stream>>>(w1, w1h, w1l, DM, DI);
    k_wprep<<<dim3(DM / 32, DI / 32), 256, 0, stream>>>(w2, w2h, w2l, DI, DM);

    k_attn_ln1<<<ROWS, 256, 0, stream>>>(enc, mask, wq, bq, wk, bk, wv, bv, g1, be1,
                                         x, xh, xl);

    // GEMM1: h = relu(x @ w1 + b1) -> bf16 hi/lo  (M=8192, N=3072, K=768), grid 24x32=768
    k_gemm8<1, 1, 0><<<dim3(DI / 128, ROWS / 256, 1), 512, 0, stream>>>(
        xh, xl, w1h, w1l, b1, nullptr, hh, hl, ROWS, DI, DM);

    // y = x + b2, then GEMM2 atomically accumulates h @ w2 (split-K=4, grid 6x32x4=768)
    k_yinit<<<(ROWS * DM / 4) / 256, 256, 0, stream>>>(x, b2, y);
    k_gemm8<4, 0, 1><<<dim3(DM / 128, ROWS / 256, 4), 512, 0, stream>>>(
        hh, hl, w2h, w2l, nullptr, y, nullptr, nullptr, ROWS, DM, DI);

    k_ln2<<<ROWS, 256, 0, stream>>>(y, g2, be2, out);
}

// Round 5
// 396.791 us; speedup vs baseline: 1.1564x; 1.1453x over previous
//
#include <hip/hip_runtime.h>

#define ROWS 8192
#define LW 96
#define HW 8
#define DM 768
#define DI 3072

typedef __bf16 bf16x8 __attribute__((ext_vector_type(8)));
typedef float f32x4 __attribute__((ext_vector_type(4)));
typedef unsigned short u16;

__device__ __forceinline__ u16 bfbits(__bf16 b) {
    return __builtin_bit_cast(u16, b);
}
__device__ __forceinline__ void decomp(float v, u16& hi, u16& lo) {
    __bf16 hb = (__bf16)v;
    float hf = (float)hb;
    __bf16 lb = (__bf16)(v - hf);
    hi = bfbits(hb); lo = bfbits(lb);
}
__device__ __forceinline__ void gload16(const void* g, void* l) {
    __builtin_amdgcn_global_load_lds((const __attribute__((address_space(1))) unsigned int*)g,
                                     (__attribute__((address_space(3))) unsigned int*)l, 16, 0, 0);
}

// ---------------- Kernel 0: weight transpose + bf16 hi/lo decompose ----------------
__global__ __launch_bounds__(256) void k_wprep(
    const float* __restrict__ W, u16* __restrict__ Th,
    u16* __restrict__ Tl, int K, int N)
{
    __shared__ float tile[32][33];
    const int tx = threadIdx.x & 31, ty = threadIdx.x >> 5;
    const int k0 = blockIdx.y * 32, n0 = blockIdx.x * 32;
#pragma unroll
    for (int i = 0; i < 32; i += 8)
        tile[ty + i][tx] = W[(size_t)(k0 + ty + i) * N + n0 + tx];
    __syncthreads();
#pragma unroll
    for (int i = 0; i < 32; i += 8) {
        int n = n0 + ty + i, k = k0 + tx;
        u16 h, l;
        decomp(tile[tx][ty + i], h, l);
        Th[(size_t)n * K + k] = h;
        Tl[(size_t)n * K + k] = l;
    }
}

// ---------------- Kernel 1: attention + residual + LN1 ----------------
// A-operand of GEMM1 is now SINGLE bf16 (B-side compensation) -> only xh out.
__global__ __launch_bounds__(256) void k_attn_ln1(
    const float* __restrict__ inp, const float* __restrict__ mask,
    const float* __restrict__ wq, const float* __restrict__ bq,
    const float* __restrict__ wk, const float* __restrict__ bk,
    const float* __restrict__ wv, const float* __restrict__ bv,
    const float* __restrict__ g1, const float* __restrict__ be1,
    float* __restrict__ xout, u16* __restrict__ xh)
{
    const int t = threadIdx.x;
    const int row = blockIdx.x;
    __shared__ float sr[DM];
    __shared__ float sq[LW], sk[LW], sv[LW], sres[LW];
    __shared__ float red[256];

    const float* rp = inp + (size_t)row * DM;
    for (int i = t; i < DM / 4; i += 256)
        ((float4*)sr)[i] = ((const float4*)rp)[i];
    __syncthreads();

    if (t < LW) {
        const float* hp = sr + t * HW;
        float aq = 0.f, ak = 0.f, av = 0.f;
#pragma unroll
        for (int i = 0; i < HW; i++) {
            float x = hp[i];
            aq += x * wq[i]; ak += x * wk[i]; av += x * wv[i];
        }
        sq[t] = aq + bq[0]; sk[t] = ak + bk[0]; sv[t] = av + bv[0];
    }
    __syncthreads();

    float pq = (t < LW) ? sq[t] * sq[t] : 0.f;
    float pk = (t < LW) ? sk[t] * sk[t] : 0.f;
    red[t] = pq; __syncthreads();
    for (int s = 128; s > 0; s >>= 1) { if (t < s) red[t] += red[t + s]; __syncthreads(); }
    float nq2 = red[0]; __syncthreads();
    red[t] = pk; __syncthreads();
    for (int s = 128; s > 0; s >>= 1) { if (t < s) red[t] += red[t + s]; __syncthreads(); }
    float nk2 = red[0]; __syncthreads();
    float inv = 1.f / fmaxf(sqrtf(nq2) * sqrtf(nk2), 1e-12f);

    float sc = -1e30f;
    if (t < LW) {
        float acc = 0.f;
        const float* mr = mask + t * LW;
        for (int kk = 0; kk < LW; kk++) acc += sk[kk] * mr[kk];
        sc = sq[t] * acc * inv;
    }
    red[t] = sc; __syncthreads();
    for (int s = 128; s > 0; s >>= 1) { if (t < s) red[t] = fmaxf(red[t], red[t + s]); __syncthreads(); }
    float mx = red[0]; __syncthreads();
    float e = (t < LW) ? __expf(sc - mx) : 0.f;
    red[t] = e; __syncthreads();
    for (int s = 128; s > 0; s >>= 1) { if (t < s) red[t] += red[t + s]; __syncthreads(); }
    float se = red[0]; __syncthreads();
    if (t < LW) sres[t] = (e / se) * sv[t];
    __syncthreads();

    float xs[3]; float sum = 0.f;
#pragma unroll
    for (int i = 0; i < 3; i++) {
        int d = t + i * 256;
        float xv = sr[d] + sres[d >> 3];
        xs[i] = xv; sum += xv;
    }
    red[t] = sum; __syncthreads();
    for (int s = 128; s > 0; s >>= 1) { if (t < s) red[t] += red[t + s]; __syncthreads(); }
    float mean = red[0] * (1.f / DM); __syncthreads();
    float vs = 0.f;
#pragma unroll
    for (int i = 0; i < 3; i++) { float dd = xs[i] - mean; vs += dd * dd; }
    red[t] = vs; __syncthreads();
    for (int s = 128; s > 0; s >>= 1) { if (t < s) red[t] += red[t + s]; __syncthreads(); }
    float rstd = rsqrtf(red[0] * (1.f / DM) + 1e-6f);

    float* xo = xout + (size_t)row * DM;
    u16* xho = xh + (size_t)row * DM;
#pragma unroll
    for (int i = 0; i < 3; i++) {
        int d = t + i * 256;
        float v = (xs[i] - mean) * rstd * g1[d] + be1[d];
        xo[d] = v;
        xho[d] = bfbits((__bf16)v);
    }
}

// ---------------- 8-wave split-bf16 MFMA GEMM, 256x128 tile, BK=32 ----------------
// 2-term B-compensated: C ~= Abf16 @ (Bh + Bl). A single bf16 (M x K) row-major;
// B pre-transposed (N x K) hi/lo bf16. LDS ring of 3 x 32KB (96 KB), counted
// vmcnt(4) (never 0 mid-loop), prefetch distance 2, tile-level sync verified r4.
// NEW (T3): per K-tile, 4 fine phases {ds_read next quadrant ; barrier ;
// lgkmcnt(0) ; setprio(1) ; 8 MFMA ; setprio(0) ; barrier} -- phase barriers are
// pure scheduling rhythm (all phases read the same certified buffer; no new race
// surface vs the r4-verified tile loop).
template<int SPLITK, int RELU, int OUT_MODE>
__global__ __launch_bounds__(512, 2) void k_gemm8(
    const u16* __restrict__ Ah,
    const u16* __restrict__ Bh, const u16* __restrict__ Bl,
    const float* __restrict__ bias, float* __restrict__ Cf,
    u16* __restrict__ Ch, int M, int N, int K)
{
    // per-buffer u16 offsets: Ah [0,8192)  Bh [8192,12288)  Bl [12288,16384)
    __shared__ u16 S[3 * 16384];   // 96 KB

    const int t = threadIdx.x;
    const int lane = t & 63, w = t >> 6;
    const int wm = w >> 1, wn = w & 1;          // 4 M-waves x 2 N-waves
    const int fr = lane & 15, fq = lane >> 4;

    // bijective XCD swizzle on the flat block index (grid size % 8 == 0)
    const int gn = gridDim.x, gm = gridDim.y;
    int Lidx = blockIdx.x + gn * (blockIdx.y + gm * blockIdx.z);
    const int nb = gn * gm * SPLITK;
    int sID = ((nb & 7) == 0) ? ((Lidx & 7) * (nb >> 3) + (Lidx >> 3)) : Lidx;
    const int bz = sID / (gn * gm);
    const int r2 = sID - bz * (gn * gm);
    const int bm = r2 / gn;
    const int bn = r2 - bm * gn;

    const int KS = K / SPLITK;
    const int NT = KS / 32;
    const int kb = bz * KS;

    // staging addresses (r4-verified math): thread t -> row r0 = t>>2,
    // swizzled source chunk c0 = (t&3)^((r0>>1)&3); +128 rows keeps c0.
    const int r0 = t >> 2;
    const int c0 = (t & 3) ^ ((r0 >> 1) & 3);
    const size_t aoff  = (size_t)(bm * 256 + r0) * K + kb + c0 * 8;
    const size_t aoff2 = aoff + (size_t)128 * K;
    const size_t boff  = (size_t)(bn * 128 + r0) * K + kb + c0 * 8;
    const int w512 = w * 512;

    f32x4 acc[4][4];
#pragma unroll
    for (int i = 0; i < 4; i++)
#pragma unroll
        for (int j = 0; j < 4; j++) acc[i][j] = (f32x4)0.f;

    // frag-read LDS indices (u16 units), loop-invariant; <=2-way bank alias (free)
    int ai[4], bi[4];
#pragma unroll
    for (int i = 0; i < 4; i++) { int rA = wm * 64 + i * 16 + fr; ai[i] = rA * 32 + (fq ^ ((rA >> 1) & 3)) * 8; }
#pragma unroll
    for (int j = 0; j < 4; j++) { int rB = wn * 64 + j * 16 + fr; bi[j] = rB * 32 + (fq ^ ((rB >> 1) & 3)) * 8; }

#define STAGE(tile, bb)                                                  \
    { u16* Lb = S + (bb) * 16384 + w512;                                 \
      const size_t kk = (size_t)(tile) * 32;                             \
      gload16(Ah + aoff  + kk, Lb + 0);                                  \
      gload16(Ah + aoff2 + kk, Lb + 4096);                               \
      gload16(Bh + boff  + kk, Lb + 8192);                               \
      gload16(Bl + boff  + kk, Lb + 12288); }

#define MM(ii, jj, AA, BH, BL)                                                            \
    acc[ii][jj] = __builtin_amdgcn_mfma_f32_16x16x32_bf16(AA, BH, acc[ii][jj], 0, 0, 0);  \
    acc[ii][jj] = __builtin_amdgcn_mfma_f32_16x16x32_bf16(AA, BL, acc[ii][jj], 0, 0, 0);

    STAGE(0, 0);
    STAGE(1, 1);

    for (int tt = 0; tt < NT; ++tt) {
        // tile-level correctness sync (verified r4): own-wave vmcnt wait, then
        // barrier => ALL waves' tile-tt loads are in LDS.
        if (tt + 1 < NT) { asm volatile("s_waitcnt vmcnt(4)" ::: "memory"); }
        else             { asm volatile("s_waitcnt vmcnt(0)" ::: "memory"); }
        __builtin_amdgcn_s_barrier();

        const u16* Lp = S + (tt % 3) * 16384;

        // ---- phase 0: read quadrant-0 frags, issue next-next tile stage ----
        bf16x8 a0  = *(const bf16x8*)&Lp[ai[0]];
        bf16x8 a1  = *(const bf16x8*)&Lp[ai[1]];
        bf16x8 bh0 = *(const bf16x8*)&Lp[ 8192 + bi[0]];
        bf16x8 bl0 = *(const bf16x8*)&Lp[12288 + bi[0]];
        bf16x8 bh1 = *(const bf16x8*)&Lp[ 8192 + bi[1]];
        bf16x8 bl1 = *(const bf16x8*)&Lp[12288 + bi[1]];
        if (tt + 2 < NT) STAGE(tt + 2, (tt + 2) % 3);
        __builtin_amdgcn_s_barrier();
        asm volatile("s_waitcnt lgkmcnt(0)" ::: "memory");
        __builtin_amdgcn_s_setprio(1);
        MM(0, 0, a0, bh0, bl0) MM(1, 0, a1, bh0, bl0)
        MM(0, 1, a0, bh1, bl1) MM(1, 1, a1, bh1, bl1)
        __builtin_amdgcn_s_setprio(0);
        __builtin_amdgcn_s_barrier();

        // ---- phase 1: read B quadrant 2,3 ----
        bf16x8 bh2 = *(const bf16x8*)&Lp[ 8192 + bi[2]];
        bf16x8 bl2 = *(const bf16x8*)&Lp[12288 + bi[2]];
        bf16x8 bh3 = *(const bf16x8*)&Lp[ 8192 + bi[3]];
        bf16x8 bl3 = *(const bf16x8*)&Lp[12288 + bi[3]];
        __builtin_amdgcn_s_barrier();
        asm volatile("s_waitcnt lgkmcnt(0)" ::: "memory");
        __builtin_amdgcn_s_setprio(1);
        MM(0, 2, a0, bh2, bl2) MM(1, 2, a1, bh2, bl2)
        MM(0, 3, a0, bh3, bl3) MM(1, 3, a1, bh3, bl3)
        __builtin_amdgcn_s_setprio(0);
        __builtin_amdgcn_s_barrier();

        // ---- phase 2: read A frags 2,3 ----
        bf16x8 a2 = *(const bf16x8*)&Lp[ai[2]];
        bf16x8 a3 = *(const bf16x8*)&Lp[ai[3]];
        __builtin_amdgcn_s_barrier();
        asm volatile("s_waitcnt lgkmcnt(0)" ::: "memory");
        __builtin_amdgcn_s_setprio(1);
        MM(2, 2, a2, bh2, bl2) MM(3, 2, a3, bh2, bl2)
        MM(2, 3, a2, bh3, bl3) MM(3, 3, a3, bh3, bl3)
        __builtin_amdgcn_s_setprio(0);
        __builtin_amdgcn_s_barrier();

        // ---- phase 3: register-only (bh0/bl0/bh1/bl1 still live) ----
        __builtin_amdgcn_s_setprio(1);
        MM(2, 0, a2, bh0, bl0) MM(3, 0, a3, bh0, bl0)
        MM(2, 1, a2, bh1, bl1) MM(3, 1, a3, bh1, bl1)
        __builtin_amdgcn_s_setprio(0);
    }
#undef STAGE
#undef MM

    // epilogue: C/D frag layout col = lane&15, row = (lane>>4)*4 + reg
#pragma unroll
    for (int i = 0; i < 4; i++) {
        const int row = bm * 256 + wm * 64 + i * 16 + fq * 4;
#pragma unroll
        for (int j = 0; j < 4; j++) {
            const int col = bn * 128 + wn * 64 + j * 16 + fr;
            if (OUT_MODE == 0) {
                const float bb = bias[col];
#pragma unroll
                for (int rg = 0; rg < 4; rg++) {
                    size_t off = (size_t)(row + rg) * N + col;
                    float v = acc[i][j][rg] + bb;
                    if (RELU) v = fmaxf(v, 0.f);
                    Ch[off] = bfbits((__bf16)v);
                }
            } else {
#pragma unroll
                for (int rg = 0; rg < 4; rg++) {
                    size_t off = (size_t)(row + rg) * N + col;
                    atomicAdd(&Cf[off], acc[i][j][rg]);
                }
            }
        }
    }
}

// ---------------- y init for GEMM2 atomic accumulation: y = x + b2 ----------------
__global__ __launch_bounds__(256) void k_yinit(
    const float* __restrict__ x, const float* __restrict__ b2, float* __restrict__ y)
{
    const int i = blockIdx.x * 256 + threadIdx.x;   // float4 index
    const int col = (i % (DM / 4)) * 4;
    float4 xv = ((const float4*)x)[i];
    float4 bv = *(const float4*)&b2[col];
    xv.x += bv.x; xv.y += bv.y; xv.z += bv.z; xv.w += bv.w;
    ((float4*)y)[i] = xv;
}

// ---------------- LN2 ----------------
__global__ __launch_bounds__(256) void k_ln2(
    const float* __restrict__ X, const float* __restrict__ g, const float* __restrict__ b,
    float* __restrict__ out)
{
    const int t = threadIdx.x;
    const int row = blockIdx.x;
    __shared__ float red[256];
    const float* xp = X + (size_t)row * DM;
    float xs[3]; float sum = 0.f;
#pragma unroll
    for (int i = 0; i < 3; i++) { xs[i] = xp[t + i * 256]; sum += xs[i]; }
    red[t] = sum; __syncthreads();
    for (int s = 128; s > 0; s >>= 1) { if (t < s) red[t] += red[t + s]; __syncthreads(); }
    float mean = red[0] * (1.f / DM); __syncthreads();
    float vs = 0.f;
#pragma unroll
    for (int i = 0; i < 3; i++) { float dd = xs[i] - mean; vs += dd * dd; }
    red[t] = vs; __syncthreads();
    for (int s = 128; s > 0; s >>= 1) { if (t < s) red[t] += red[t + s]; __syncthreads(); }
    float rstd = rsqrtf(red[0] * (1.f / DM) + 1e-6f);
    float* op = out + (size_t)row * DM;
#pragma unroll
    for (int i = 0; i < 3; i++) { int d = t + i * 256; op[d] = (xs[i] - mean) * rstd * g[d] + b[d]; }
}

extern "C" void kernel_launch(void* const* d_in, const int* in_sizes, int n_in,
                              void* d_out, int out_size, void* d_ws, size_t ws_size,
                              hipStream_t stream) {
    const float* enc  = (const float*)d_in[0];
    const float* mask = (const float*)d_in[1];
    const float* wq = (const float*)d_in[2];  const float* bq = (const float*)d_in[3];
    const float* wk = (const float*)d_in[4];  const float* bk = (const float*)d_in[5];
    const float* wv = (const float*)d_in[6];  const float* bv = (const float*)d_in[7];
    const float* g1 = (const float*)d_in[8];  const float* be1 = (const float*)d_in[9];
    const float* w1 = (const float*)d_in[10]; const float* b1  = (const float*)d_in[11];
    const float* w2 = (const float*)d_in[12]; const float* b2  = (const float*)d_in[13];
    const float* g2 = (const float*)d_in[14]; const float* be2 = (const float*)d_in[15];
    float* out = (float*)d_out;

    // workspace layout (~132 MB)
    char* p = (char*)d_ws;
    float* x  = (float*)p;                 p += (size_t)ROWS * DM * 4;   // 25.2 MB
    float* y  = (float*)p;                 p += (size_t)ROWS * DM * 4;   // 25.2 MB
    u16* xh = (u16*)p; p += (size_t)ROWS * DM * 2;                       // 12.6 MB
    u16* hh = (u16*)p; p += (size_t)ROWS * DI * 2;                       // 50.3 MB
    u16* w1h = (u16*)p; p += (size_t)DM * DI * 2;                        // 4.7 MB
    u16* w1l = (u16*)p; p += (size_t)DM * DI * 2;
    u16* w2h = (u16*)p; p += (size_t)DM * DI * 2;
    u16* w2l = (u16*)p; p += (size_t)DM * DI * 2;

    k_wprep<<<dim3(DI / 32, DM / 32), 256, 0, stream>>>(w1, w1h, w1l, DM, DI);
    k_wprep<<<dim3(DM / 32, DI / 32), 256, 0, stream>>>(w2, w2h, w2l, DI, DM);

    k_attn_ln1<<<ROWS, 256, 0, stream>>>(enc, mask, wq, bq, wk, bk, wv, bv, g1, be1,
                                         x, xh);

    // GEMM1: h = relu(x @ w1 + b1) -> bf16  (M=8192, N=3072, K=768), grid 24x32=768
    k_gemm8<1, 1, 0><<<dim3(DI / 128, ROWS / 256, 1), 512, 0, stream>>>(
        xh, w1h, w1l, b1, nullptr, hh, ROWS, DI, DM);

    // y = x + b2, then GEMM2 atomically accumulates h @ w2 (split-K=4, grid 6x32x4=768)
    k_yinit<<<(ROWS * DM / 4) / 256, 256, 0, stream>>>(x, b2, y);
    k_gemm8<4, 0, 1><<<dim3(DM / 128, ROWS / 256, 4), 512, 0, stream>>>(
        hh, w2h, w2l, nullptr, y, nullptr, ROWS, DM, DI);

    k_ln2<<<ROWS, 256, 0, stream>>>(y, g2, be2, out);
}

// Round 6
// 366.073 us; speedup vs baseline: 1.2535x; 1.0839x over previous
//
#include <hip/hip_runtime.h>

#define ROWS 8192
#define LW 96
#define HW 8
#define DM 768
#define DI 3072

typedef __bf16 bf16x8 __attribute__((ext_vector_type(8)));
typedef float f32x4 __attribute__((ext_vector_type(4)));
typedef unsigned short u16;

__device__ __forceinline__ u16 bfbits(__bf16 b) {
    return __builtin_bit_cast(u16, b);
}
__device__ __forceinline__ void decomp(float v, u16& hi, u16& lo) {
    __bf16 hb = (__bf16)v;
    float hf = (float)hb;
    __bf16 lb = (__bf16)(v - hf);
    hi = bfbits(hb); lo = bfbits(lb);
}
__device__ __forceinline__ void gload16(const void* g, void* l) {
    __builtin_amdgcn_global_load_lds((const __attribute__((address_space(1))) unsigned int*)g,
                                     (__attribute__((address_space(3))) unsigned int*)l, 16, 0, 0);
}

// ---------------- Kernel 0: weight transpose + bf16 hi/lo decompose ----------------
__global__ __launch_bounds__(256) void k_wprep(
    const float* __restrict__ W, u16* __restrict__ Th,
    u16* __restrict__ Tl, int K, int N)
{
    __shared__ float tile[32][33];
    const int tx = threadIdx.x & 31, ty = threadIdx.x >> 5;
    const int k0 = blockIdx.y * 32, n0 = blockIdx.x * 32;
#pragma unroll
    for (int i = 0; i < 32; i += 8)
        tile[ty + i][tx] = W[(size_t)(k0 + ty + i) * N + n0 + tx];
    __syncthreads();
#pragma unroll
    for (int i = 0; i < 32; i += 8) {
        int n = n0 + ty + i, k = k0 + tx;
        u16 h, l;
        decomp(tile[tx][ty + i], h, l);
        Th[(size_t)n * K + k] = h;
        Tl[(size_t)n * K + k] = l;
    }
}

// ---------------- Kernel 1: attention + residual + LN1 ----------------
__global__ __launch_bounds__(256) void k_attn_ln1(
    const float* __restrict__ inp, const float* __restrict__ mask,
    const float* __restrict__ wq, const float* __restrict__ bq,
    const float* __restrict__ wk, const float* __restrict__ bk,
    const float* __restrict__ wv, const float* __restrict__ bv,
    const float* __restrict__ g1, const float* __restrict__ be1,
    float* __restrict__ xout, u16* __restrict__ xh)
{
    const int t = threadIdx.x;
    const int row = blockIdx.x;
    __shared__ float sr[DM];
    __shared__ float sq[LW], sk[LW], sv[LW], sres[LW];
    __shared__ float red[256];

    const float* rp = inp + (size_t)row * DM;
    for (int i = t; i < DM / 4; i += 256)
        ((float4*)sr)[i] = ((const float4*)rp)[i];
    __syncthreads();

    if (t < LW) {
        const float* hp = sr + t * HW;
        float aq = 0.f, ak = 0.f, av = 0.f;
#pragma unroll
        for (int i = 0; i < HW; i++) {
            float x = hp[i];
            aq += x * wq[i]; ak += x * wk[i]; av += x * wv[i];
        }
        sq[t] = aq + bq[0]; sk[t] = ak + bk[0]; sv[t] = av + bv[0];
    }
    __syncthreads();

    float pq = (t < LW) ? sq[t] * sq[t] : 0.f;
    float pk = (t < LW) ? sk[t] * sk[t] : 0.f;
    red[t] = pq; __syncthreads();
    for (int s = 128; s > 0; s >>= 1) { if (t < s) red[t] += red[t + s]; __syncthreads(); }
    float nq2 = red[0]; __syncthreads();
    red[t] = pk; __syncthreads();
    for (int s = 128; s > 0; s >>= 1) { if (t < s) red[t] += red[t + s]; __syncthreads(); }
    float nk2 = red[0]; __syncthreads();
    float inv = 1.f / fmaxf(sqrtf(nq2) * sqrtf(nk2), 1e-12f);

    float sc = -1e30f;
    if (t < LW) {
        float acc = 0.f;
        const float* mr = mask + t * LW;
        for (int kk = 0; kk < LW; kk++) acc += sk[kk] * mr[kk];
        sc = sq[t] * acc * inv;
    }
    red[t] = sc; __syncthreads();
    for (int s = 128; s > 0; s >>= 1) { if (t < s) red[t] = fmaxf(red[t], red[t + s]); __syncthreads(); }
    float mx = red[0]; __syncthreads();
    float e = (t < LW) ? __expf(sc - mx) : 0.f;
    red[t] = e; __syncthreads();
    for (int s = 128; s > 0; s >>= 1) { if (t < s) red[t] += red[t + s]; __syncthreads(); }
    float se = red[0]; __syncthreads();
    if (t < LW) sres[t] = (e / se) * sv[t];
    __syncthreads();

    float xs[3]; float sum = 0.f;
#pragma unroll
    for (int i = 0; i < 3; i++) {
        int d = t + i * 256;
        float xv = sr[d] + sres[d >> 3];
        xs[i] = xv; sum += xv;
    }
    red[t] = sum; __syncthreads();
    for (int s = 128; s > 0; s >>= 1) { if (t < s) red[t] += red[t + s]; __syncthreads(); }
    float mean = red[0] * (1.f / DM); __syncthreads();
    float vs = 0.f;
#pragma unroll
    for (int i = 0; i < 3; i++) { float dd = xs[i] - mean; vs += dd * dd; }
    red[t] = vs; __syncthreads();
    for (int s = 128; s > 0; s >>= 1) { if (t < s) red[t] += red[t + s]; __syncthreads(); }
    float rstd = rsqrtf(red[0] * (1.f / DM) + 1e-6f);

    float* xo = xout + (size_t)row * DM;
    u16* xho = xh + (size_t)row * DM;
#pragma unroll
    for (int i = 0; i < 3; i++) {
        int d = t + i * 256;
        float v = (xs[i] - mean) * rstd * g1[d] + be1[d];
        xo[d] = v;
        xho[d] = bfbits((__bf16)v);
    }
}

// ---------------- 4-wave 2-term MFMA GEMM, 128x128 tile, BK=32 ----------------
// C ~= Abf16 @ (Bh + Bl). A single bf16 (M x K) row-major; B pre-transposed
// (N x K) hi/lo bf16. Ring-2 LDS of 24KB slots (48KB total -> 3 blocks/CU),
// classic 2-barrier loop with counted vmcnt (never 0 mid-loop), prefetch
// distance 1; cross-block TLP covers residual latency (m97/m114 pattern).
// Per-slot u16 layout: A [0,4096) Bh [4096,8192) Bl [8192,12288).
template<int SPLITK, int RELU, int OUT_MODE>
__global__ __launch_bounds__(256, 3) void k_gemm4(
    const u16* __restrict__ Ah,
    const u16* __restrict__ Bh, const u16* __restrict__ Bl,
    const float* __restrict__ bias, float* __restrict__ Cf,
    u16* __restrict__ Ch, int M, int N, int K)
{
    __shared__ u16 S[2 * 12288];   // 48 KB

    const int t = threadIdx.x;
    const int lane = t & 63, w = t >> 6;
    const int wm = w >> 1, wn = w & 1;          // 2 M-waves x 2 N-waves
    const int fr = lane & 15, fq = lane >> 4;

    // bijective XCD swizzle on the flat block index (grid size % 8 == 0)
    const int gn = gridDim.x, gm = gridDim.y;
    int Lidx = blockIdx.x + gn * (blockIdx.y + gm * blockIdx.z);
    const int nb = gn * gm * SPLITK;
    int sID = ((nb & 7) == 0) ? ((Lidx & 7) * (nb >> 3) + (Lidx >> 3)) : Lidx;
    const int bz = sID / (gn * gm);
    const int rr = sID - bz * (gn * gm);
    const int bm = rr / gn;
    const int bn = rr - bm * gn;

    const int KS = K / SPLITK;
    const int NT = KS / 32;
    const int kb = bz * KS;

    // staging (verified r2/r4 math): chunk s -> row r=s>>2, lds chunk c'=s&3,
    // source chunk c = c' ^ ((r>>1)&3). Thread t covers chunks t and t+256
    // (row +64 keeps (r>>1)&3, so same c).
    const int r0 = t >> 2;                       // 0..63
    const int c0 = (t & 3) ^ ((r0 >> 1) & 3);
    const size_t aoff  = (size_t)(bm * 128 + r0) * K + kb + c0 * 8;
    const size_t aoff2 = aoff + (size_t)64 * K;
    const size_t boff  = (size_t)(bn * 128 + r0) * K + kb + c0 * 8;
    const size_t boff2 = boff + (size_t)64 * K;
    const int w512 = w * 512;                    // wave-uniform u16 offset

    f32x4 acc[4][4];
#pragma unroll
    for (int i = 0; i < 4; i++)
#pragma unroll
        for (int j = 0; j < 4; j++) acc[i][j] = (f32x4)0.f;

    // frag-read LDS indices (u16 units), loop-invariant; <=2-way bank alias (free)
    int ai[4], bi[4];
#pragma unroll
    for (int i = 0; i < 4; i++) { int rA = wm * 64 + i * 16 + fr; ai[i] = rA * 32 + (fq ^ ((rA >> 1) & 3)) * 8; }
#pragma unroll
    for (int j = 0; j < 4; j++) { int rB = wn * 64 + j * 16 + fr; bi[j] = rB * 32 + (fq ^ ((rB >> 1) & 3)) * 8; }

#define STAGE(tile, bb)                                                  \
    { u16* Lb = S + (bb) * 12288 + w512;                                 \
      const size_t kk = (size_t)(tile) * 32;                             \
      gload16(Ah + aoff  + kk, Lb + 0);                                  \
      gload16(Ah + aoff2 + kk, Lb + 2048);                               \
      gload16(Bh + boff  + kk, Lb + 4096);                               \
      gload16(Bh + boff2 + kk, Lb + 6144);                               \
      gload16(Bl + boff  + kk, Lb + 8192);                               \
      gload16(Bl + boff2 + kk, Lb + 10240); }

#define MM(ii, jj, AA, BH, BL)                                                            \
    acc[ii][jj] = __builtin_amdgcn_mfma_f32_16x16x32_bf16(AA, BH, acc[ii][jj], 0, 0, 0);  \
    acc[ii][jj] = __builtin_amdgcn_mfma_f32_16x16x32_bf16(AA, BL, acc[ii][jj], 0, 0, 0);

    STAGE(0, 0);

    for (int tt = 0; tt < NT; ++tt) {
        // stage next tile into the other slot, then certify tile tt landed:
        // own-wave counted vmcnt BEFORE barrier (r4-verified ordering).
        if (tt + 1 < NT) {
            STAGE(tt + 1, (tt + 1) & 1);
            asm volatile("s_waitcnt vmcnt(6)" ::: "memory");
        } else {
            asm volatile("s_waitcnt vmcnt(0)" ::: "memory");
        }
        __builtin_amdgcn_s_barrier();

        const u16* Lp = S + (tt & 1) * 12288;
        bf16x8 a[4], bh[4], bl[4];
#pragma unroll
        for (int j = 0; j < 4; j++) {
            bh[j] = *(const bf16x8*)&Lp[4096 + bi[j]];
            bl[j] = *(const bf16x8*)&Lp[8192 + bi[j]];
        }
#pragma unroll
        for (int i = 0; i < 4; i++) a[i] = *(const bf16x8*)&Lp[ai[i]];

        __builtin_amdgcn_s_setprio(1);
#pragma unroll
        for (int j = 0; j < 4; j++)
#pragma unroll
            for (int i = 0; i < 4; i++) { MM(i, j, a[i], bh[j], bl[j]) }
        __builtin_amdgcn_s_setprio(0);

        // WAR fence: next iteration's STAGE overwrites this slot only after
        // every wave has consumed it.
        __builtin_amdgcn_s_barrier();
    }
#undef STAGE
#undef MM

    // epilogue: C/D frag layout col = lane&15, row = (lane>>4)*4 + reg
#pragma unroll
    for (int i = 0; i < 4; i++) {
        const int row = bm * 128 + wm * 64 + i * 16 + fq * 4;
#pragma unroll
        for (int j = 0; j < 4; j++) {
            const int col = bn * 128 + wn * 64 + j * 16 + fr;
            if (OUT_MODE == 0) {
                const float bb = bias[col];
#pragma unroll
                for (int rg = 0; rg < 4; rg++) {
                    size_t off = (size_t)(row + rg) * N + col;
                    float v = acc[i][j][rg] + bb;
                    if (RELU) v = fmaxf(v, 0.f);
                    Ch[off] = bfbits((__bf16)v);
                }
            } else {
#pragma unroll
                for (int rg = 0; rg < 4; rg++) {
                    size_t off = (size_t)(row + rg) * N + col;
                    atomicAdd(&Cf[off], acc[i][j][rg]);
                }
            }
        }
    }
}

// ---------------- y init for GEMM2 atomic accumulation: y = x + b2 ----------------
__global__ __launch_bounds__(256) void k_yinit(
    const float* __restrict__ x, const float* __restrict__ b2, float* __restrict__ y)
{
    const int i = blockIdx.x * 256 + threadIdx.x;   // float4 index
    const int col = (i % (DM / 4)) * 4;
    float4 xv = ((const float4*)x)[i];
    float4 bv = *(const float4*)&b2[col];
    xv.x += bv.x; xv.y += bv.y; xv.z += bv.z; xv.w += bv.w;
    ((float4*)y)[i] = xv;
}

// ---------------- LN2 ----------------
__global__ __launch_bounds__(256) void k_ln2(
    const float* __restrict__ X, const float* __restrict__ g, const float* __restrict__ b,
    float* __restrict__ out)
{
    const int t = threadIdx.x;
    const int row = blockIdx.x;
    __shared__ float red[256];
    const float* xp = X + (size_t)row * DM;
    float xs[3]; float sum = 0.f;
#pragma unroll
    for (int i = 0; i < 3; i++) { xs[i] = xp[t + i * 256]; sum += xs[i]; }
    red[t] = sum; __syncthreads();
    for (int s = 128; s > 0; s >>= 1) { if (t < s) red[t] += red[t + s]; __syncthreads(); }
    float mean = red[0] * (1.f / DM); __syncthreads();
    float vs = 0.f;
#pragma unroll
    for (int i = 0; i < 3; i++) { float dd = xs[i] - mean; vs += dd * dd; }
    red[t] = vs; __syncthreads();
    for (int s = 128; s > 0; s >>= 1) { if (t < s) red[t] += red[t + s]; __syncthreads(); }
    float rstd = rsqrtf(red[0] * (1.f / DM) + 1e-6f);
    float* op = out + (size_t)row * DM;
#pragma unroll
    for (int i = 0; i < 3; i++) { int d = t + i * 256; op[d] = (xs[i] - mean) * rstd * g[d] + b[d]; }
}

extern "C" void kernel_launch(void* const* d_in, const int* in_sizes, int n_in,
                              void* d_out, int out_size, void* d_ws, size_t ws_size,
                              hipStream_t stream) {
    const float* enc  = (const float*)d_in[0];
    const float* mask = (const float*)d_in[1];
    const float* wq = (const float*)d_in[2];  const float* bq = (const float*)d_in[3];
    const float* wk = (const float*)d_in[4];  const float* bk = (const float*)d_in[5];
    const float* wv = (const float*)d_in[6];  const float* bv = (const float*)d_in[7];
    const float* g1 = (const float*)d_in[8];  const float* be1 = (const float*)d_in[9];
    const float* w1 = (const float*)d_in[10]; const float* b1  = (const float*)d_in[11];
    const float* w2 = (const float*)d_in[12]; const float* b2  = (const float*)d_in[13];
    const float* g2 = (const float*)d_in[14]; const float* be2 = (const float*)d_in[15];
    float* out = (float*)d_out;

    // workspace layout (~132 MB)
    char* p = (char*)d_ws;
    float* x  = (float*)p;                 p += (size_t)ROWS * DM * 4;   // 25.2 MB
    float* y  = (float*)p;                 p += (size_t)ROWS * DM * 4;   // 25.2 MB
    u16* xh = (u16*)p; p += (size_t)ROWS * DM * 2;                       // 12.6 MB
    u16* hh = (u16*)p; p += (size_t)ROWS * DI * 2;                       // 50.3 MB
    u16* w1h = (u16*)p; p += (size_t)DM * DI * 2;                        // 4.7 MB
    u16* w1l = (u16*)p; p += (size_t)DM * DI * 2;
    u16* w2h = (u16*)p; p += (size_t)DM * DI * 2;
    u16* w2l = (u16*)p; p += (size_t)DM * DI * 2;

    k_wprep<<<dim3(DI / 32, DM / 32), 256, 0, stream>>>(w1, w1h, w1l, DM, DI);
    k_wprep<<<dim3(DM / 32, DI / 32), 256, 0, stream>>>(w2, w2h, w2l, DI, DM);

    k_attn_ln1<<<ROWS, 256, 0, stream>>>(enc, mask, wq, bq, wk, bk, wv, bv, g1, be1,
                                         x, xh);

    // GEMM1: h = relu(x @ w1 + b1) -> bf16  (M=8192, N=3072, K=768), grid 24x64=1536
    k_gemm4<1, 1, 0><<<dim3(DI / 128, ROWS / 128, 1), 256, 0, stream>>>(
        xh, w1h, w1l, b1, nullptr, hh, ROWS, DI, DM);

    // y = x + b2, then GEMM2 atomically accumulates h @ w2 (split-K=2, grid 6x64x2=768)
    k_yinit<<<(ROWS * DM / 4) / 256, 256, 0, stream>>>(x, b2, y);
    k_gemm4<2, 0, 1><<<dim3(DM / 128, ROWS / 128, 2), 256, 0, stream>>>(
        hh, w2h, w2l, nullptr, y, nullptr, ROWS, DM, DI);

    k_ln2<<<ROWS, 256, 0, stream>>>(y, g2, be2, out);
}

// Round 7
// 316.244 us; speedup vs baseline: 1.4510x; 1.1576x over previous
//
#include <hip/hip_runtime.h>

#define ROWS 8192
#define LW 96
#define HW 8
#define DM 768
#define DI 3072

typedef __bf16 bf16x8 __attribute__((ext_vector_type(8)));
typedef float f32x4 __attribute__((ext_vector_type(4)));
typedef unsigned short u16;
typedef unsigned int u32;

__device__ __forceinline__ u16 bfbits(__bf16 b) {
    return __builtin_bit_cast(u16, b);
}
__device__ __forceinline__ void decomp(float v, u16& hi, u16& lo) {
    __bf16 hb = (__bf16)v;
    float hf = (float)hb;
    __bf16 lb = (__bf16)(v - hf);
    hi = bfbits(hb); lo = bfbits(lb);
}
__device__ __forceinline__ void gload16(const void* g, void* l) {
    __builtin_amdgcn_global_load_lds((const __attribute__((address_space(1))) unsigned int*)g,
                                     (__attribute__((address_space(3))) unsigned int*)l, 16, 0, 0);
}
__device__ __forceinline__ float wred_sum(float v) {
#pragma unroll
    for (int o = 32; o; o >>= 1) v += __shfl_xor(v, o);
    return v;
}
__device__ __forceinline__ float wred_max(float v) {
#pragma unroll
    for (int o = 32; o; o >>= 1) v = fmaxf(v, __shfl_xor(v, o));
    return v;
}

// ---------------- Kernel 0: weight transpose + bf16 hi/lo decompose ----------------
__global__ __launch_bounds__(256) void k_wprep(
    const float* __restrict__ W, u16* __restrict__ Th,
    u16* __restrict__ Tl, int K, int N)
{
    __shared__ float tile[32][33];
    const int tx = threadIdx.x & 31, ty = threadIdx.x >> 5;
    const int k0 = blockIdx.y * 32, n0 = blockIdx.x * 32;
#pragma unroll
    for (int i = 0; i < 32; i += 8)
        tile[ty + i][tx] = W[(size_t)(k0 + ty + i) * N + n0 + tx];
    __syncthreads();
#pragma unroll
    for (int i = 0; i < 32; i += 8) {
        int n = n0 + ty + i, k = k0 + tx;
        u16 h, l;
        decomp(tile[tx][ty + i], h, l);
        Th[(size_t)n * K + k] = h;
        Tl[(size_t)n * K + k] = l;
    }
}

// ---------------- Kernel 1: attention + residual + LN1, wave-per-row ----------------
// Zero __syncthreads: 4 independent waves/block, all reductions via shfl_xor.
// mask is Toeplitz: mask[j,k] = g[95-j+k]; g[0..190] reconstructed from
// mask[95][m] (m<96) and mask[190-m][95] (m>=96). Lane owns windows lane and
// 64+lane (lane<32), i.e. elements [8*lane,8*lane+8) and [512+8*lane,...).
__global__ __launch_bounds__(256) void k_attn_ln1(
    const float* __restrict__ inp, const float* __restrict__ mask,
    const float* __restrict__ wq, const float* __restrict__ bq,
    const float* __restrict__ wk, const float* __restrict__ bk,
    const float* __restrict__ wv, const float* __restrict__ bv,
    const float* __restrict__ g1, const float* __restrict__ be1,
    float* __restrict__ xout, u16* __restrict__ xh)
{
    const int t = threadIdx.x, lane = t & 63, w = t >> 6;
    const int row = blockIdx.x * 4 + w;
    __shared__ float kvS[4][96];
    __shared__ float gS[4][192];

    const float* rp = inp + (size_t)row * DM;

    // own-window loads
    float xr[8], xr2[8];
    {
        float4 a = ((const float4*)rp)[lane * 2];
        float4 b = ((const float4*)rp)[lane * 2 + 1];
        xr[0]=a.x; xr[1]=a.y; xr[2]=a.z; xr[3]=a.w;
        xr[4]=b.x; xr[5]=b.y; xr[6]=b.z; xr[7]=b.w;
    }
    if (lane < 32) {
        float4 a = ((const float4*)rp)[128 + lane * 2];
        float4 b = ((const float4*)rp)[128 + lane * 2 + 1];
        xr2[0]=a.x; xr2[1]=a.y; xr2[2]=a.z; xr2[3]=a.w;
        xr2[4]=b.x; xr2[5]=b.y; xr2[6]=b.z; xr2[7]=b.w;
    } else {
#pragma unroll
        for (int i = 0; i < 8; i++) xr2[i] = 0.f;
    }

    // gather gaussian vector g[0..190] into per-wave LDS
    {
        int m1 = lane;                       // 0..63
        gS[w][m1] = mask[95 * LW + m1];
        int m2 = 64 + lane;                  // 64..127
        gS[w][m2] = (m2 < 96) ? mask[95 * LW + m2] : mask[(190 - m2) * LW + 95];
        int m3 = 128 + lane;                 // 128..191
        if (m3 <= 190) gS[w][m3] = mask[(190 - m3) * LW + 95];
    }

    // q/k/v for own windows
    float q1, k1, v1, q2, k2, v2;
    {
        float aq = 0.f, ak = 0.f, av = 0.f, aq2 = 0.f, ak2 = 0.f, av2 = 0.f;
#pragma unroll
        for (int i = 0; i < 8; i++) {
            float wqi = wq[i], wki = wk[i], wvi = wv[i];
            aq = fmaf(xr[i],  wqi, aq);  ak = fmaf(xr[i],  wki, ak);  av = fmaf(xr[i],  wvi, av);
            aq2 = fmaf(xr2[i], wqi, aq2); ak2 = fmaf(xr2[i], wki, ak2); av2 = fmaf(xr2[i], wvi, av2);
        }
        q1 = aq + bq[0]; k1 = ak + bk[0]; v1 = av + bv[0];
        q2 = aq2 + bq[0]; k2 = ak2 + bk[0]; v2 = av2 + bv[0];
    }

    kvS[w][lane] = k1;
    if (lane < 32) kvS[w][64 + lane] = k2;
    // wave-coherent LDS: all same-wave writes land before reads after this fence
    asm volatile("s_waitcnt lgkmcnt(0)" ::: "memory");

    // norms
    float nq2 = wred_sum(q1 * q1 + (lane < 32 ? q2 * q2 : 0.f));
    float nk2 = wred_sum(k1 * k1 + (lane < 32 ? k2 * k2 : 0.f));
    float inv = 1.f / fmaxf(sqrtf(nq2) * sqrtf(nk2), 1e-12f);

    // km[j] = sum_k g[95-j+k]*k[k]  (Toeplitz mask matvec)
    float km1 = 0.f, km2 = 0.f;
    {
        const float* gw = gS[w];
        const float* kw = kvS[w];
        const int b1 = 95 - lane;
        const int b2 = (lane < 32) ? (31 - lane) : 0;
#pragma unroll 4
        for (int kk = 0; kk < 96; kk++) {
            float kv = kw[kk];
            km1 = fmaf(gw[b1 + kk], kv, km1);
            km2 = fmaf(gw[b2 + kk], kv, km2);
        }
    }

    // softmax over 96 windows
    float sc1 = q1 * km1 * inv;
    float sc2 = (lane < 32) ? (q2 * km2 * inv) : -1e30f;
    float mx = wred_max(fmaxf(sc1, sc2));
    float e1 = __expf(sc1 - mx);
    float e2 = (lane < 32) ? __expf(sc2 - mx) : 0.f;
    float se = wred_sum(e1 + e2);
    float r1 = (e1 / se) * v1;
    float r2 = (e2 / se) * v2;

    // residual + LN1
    float xn[8], xn2[8];
    float sum = 0.f;
#pragma unroll
    for (int i = 0; i < 8; i++) { xn[i] = xr[i] + r1; sum += xn[i]; }
    if (lane < 32) {
#pragma unroll
        for (int i = 0; i < 8; i++) { xn2[i] = xr2[i] + r2; sum += xn2[i]; }
    }
    float mean = wred_sum(sum) * (1.f / DM);
    float vs = 0.f;
#pragma unroll
    for (int i = 0; i < 8; i++) { float d = xn[i] - mean; vs += d * d; }
    if (lane < 32) {
#pragma unroll
        for (int i = 0; i < 8; i++) { float d = xn2[i] - mean; vs += d * d; }
    }
    float rstd = rsqrtf(wred_sum(vs) * (1.f / DM) + 1e-6f);

    float* xo = xout + (size_t)row * DM;
    u16* xho = xh + (size_t)row * DM;
    {
        const int d0 = lane * 8;
        float4 ga = ((const float4*)(g1 + d0))[0], gb = ((const float4*)(g1 + d0))[1];
        float4 ba = ((const float4*)(be1 + d0))[0], bb = ((const float4*)(be1 + d0))[1];
        float o[8];
        o[0]=(xn[0]-mean)*rstd*ga.x+ba.x; o[1]=(xn[1]-mean)*rstd*ga.y+ba.y;
        o[2]=(xn[2]-mean)*rstd*ga.z+ba.z; o[3]=(xn[3]-mean)*rstd*ga.w+ba.w;
        o[4]=(xn[4]-mean)*rstd*gb.x+bb.x; o[5]=(xn[5]-mean)*rstd*gb.y+bb.y;
        o[6]=(xn[6]-mean)*rstd*gb.z+bb.z; o[7]=(xn[7]-mean)*rstd*gb.w+bb.w;
        ((float4*)(xo + d0))[0] = make_float4(o[0], o[1], o[2], o[3]);
        ((float4*)(xo + d0))[1] = make_float4(o[4], o[5], o[6], o[7]);
        uint4 pk;
        pk.x = (u32)bfbits((__bf16)o[0]) | ((u32)bfbits((__bf16)o[1]) << 16);
        pk.y = (u32)bfbits((__bf16)o[2]) | ((u32)bfbits((__bf16)o[3]) << 16);
        pk.z = (u32)bfbits((__bf16)o[4]) | ((u32)bfbits((__bf16)o[5]) << 16);
        pk.w = (u32)bfbits((__bf16)o[6]) | ((u32)bfbits((__bf16)o[7]) << 16);
        *(uint4*)(xho + d0) = pk;
    }
    if (lane < 32) {
        const int d0 = 512 + lane * 8;
        float4 ga = ((const float4*)(g1 + d0))[0], gb = ((const float4*)(g1 + d0))[1];
        float4 ba = ((const float4*)(be1 + d0))[0], bb = ((const float4*)(be1 + d0))[1];
        float o[8];
        o[0]=(xn2[0]-mean)*rstd*ga.x+ba.x; o[1]=(xn2[1]-mean)*rstd*ga.y+ba.y;
        o[2]=(xn2[2]-mean)*rstd*ga.z+ba.z; o[3]=(xn2[3]-mean)*rstd*ga.w+ba.w;
        o[4]=(xn2[4]-mean)*rstd*gb.x+bb.x; o[5]=(xn2[5]-mean)*rstd*gb.y+bb.y;
        o[6]=(xn2[6]-mean)*rstd*gb.z+bb.z; o[7]=(xn2[7]-mean)*rstd*gb.w+bb.w;
        ((float4*)(xo + d0))[0] = make_float4(o[0], o[1], o[2], o[3]);
        ((float4*)(xo + d0))[1] = make_float4(o[4], o[5], o[6], o[7]);
        uint4 pk;
        pk.x = (u32)bfbits((__bf16)o[0]) | ((u32)bfbits((__bf16)o[1]) << 16);
        pk.y = (u32)bfbits((__bf16)o[2]) | ((u32)bfbits((__bf16)o[3]) << 16);
        pk.z = (u32)bfbits((__bf16)o[4]) | ((u32)bfbits((__bf16)o[5]) << 16);
        pk.w = (u32)bfbits((__bf16)o[6]) | ((u32)bfbits((__bf16)o[7]) << 16);
        *(uint4*)(xho + d0) = pk;
    }
}

// ---------------- 4-wave 2-term MFMA GEMM, 128x128 tile, BK=32 ----------------
// Unchanged from r6 (verified) except OUT_MODE 1 now writes a per-bz partial
// buffer (no atomics): Cf + bz*M*N.
template<int SPLITK, int RELU, int OUT_MODE>
__global__ __launch_bounds__(256, 3) void k_gemm4(
    const u16* __restrict__ Ah,
    const u16* __restrict__ Bh, const u16* __restrict__ Bl,
    const float* __restrict__ bias, float* __restrict__ Cf,
    u16* __restrict__ Ch, int M, int N, int K)
{
    __shared__ u16 S[2 * 12288];   // 48 KB

    const int t = threadIdx.x;
    const int lane = t & 63, w = t >> 6;
    const int wm = w >> 1, wn = w & 1;          // 2 M-waves x 2 N-waves
    const int fr = lane & 15, fq = lane >> 4;

    // bijective XCD swizzle on the flat block index (grid size % 8 == 0)
    const int gn = gridDim.x, gm = gridDim.y;
    int Lidx = blockIdx.x + gn * (blockIdx.y + gm * blockIdx.z);
    const int nb = gn * gm * SPLITK;
    int sID = ((nb & 7) == 0) ? ((Lidx & 7) * (nb >> 3) + (Lidx >> 3)) : Lidx;
    const int bz = sID / (gn * gm);
    const int rr = sID - bz * (gn * gm);
    const int bm = rr / gn;
    const int bn = rr - bm * gn;

    const int KS = K / SPLITK;
    const int NT = KS / 32;
    const int kb = bz * KS;

    const int r0 = t >> 2;                       // 0..63
    const int c0 = (t & 3) ^ ((r0 >> 1) & 3);
    const size_t aoff  = (size_t)(bm * 128 + r0) * K + kb + c0 * 8;
    const size_t aoff2 = aoff + (size_t)64 * K;
    const size_t boff  = (size_t)(bn * 128 + r0) * K + kb + c0 * 8;
    const size_t boff2 = boff + (size_t)64 * K;
    const int w512 = w * 512;

    f32x4 acc[4][4];
#pragma unroll
    for (int i = 0; i < 4; i++)
#pragma unroll
        for (int j = 0; j < 4; j++) acc[i][j] = (f32x4)0.f;

    int ai[4], bi[4];
#pragma unroll
    for (int i = 0; i < 4; i++) { int rA = wm * 64 + i * 16 + fr; ai[i] = rA * 32 + (fq ^ ((rA >> 1) & 3)) * 8; }
#pragma unroll
    for (int j = 0; j < 4; j++) { int rB = wn * 64 + j * 16 + fr; bi[j] = rB * 32 + (fq ^ ((rB >> 1) & 3)) * 8; }

#define STAGE(tile, bb)                                                  \
    { u16* Lb = S + (bb) * 12288 + w512;                                 \
      const size_t kk = (size_t)(tile) * 32;                             \
      gload16(Ah + aoff  + kk, Lb + 0);                                  \
      gload16(Ah + aoff2 + kk, Lb + 2048);                               \
      gload16(Bh + boff  + kk, Lb + 4096);                               \
      gload16(Bh + boff2 + kk, Lb + 6144);                               \
      gload16(Bl + boff  + kk, Lb + 8192);                               \
      gload16(Bl + boff2 + kk, Lb + 10240); }

#define MM(ii, jj, AA, BH, BL)                                                            \
    acc[ii][jj] = __builtin_amdgcn_mfma_f32_16x16x32_bf16(AA, BH, acc[ii][jj], 0, 0, 0);  \
    acc[ii][jj] = __builtin_amdgcn_mfma_f32_16x16x32_bf16(AA, BL, acc[ii][jj], 0, 0, 0);

    STAGE(0, 0);

    for (int tt = 0; tt < NT; ++tt) {
        if (tt + 1 < NT) {
            STAGE(tt + 1, (tt + 1) & 1);
            asm volatile("s_waitcnt vmcnt(6)" ::: "memory");
        } else {
            asm volatile("s_waitcnt vmcnt(0)" ::: "memory");
        }
        __builtin_amdgcn_s_barrier();

        const u16* Lp = S + (tt & 1) * 12288;
        bf16x8 a[4], bh[4], bl[4];
#pragma unroll
        for (int j = 0; j < 4; j++) {
            bh[j] = *(const bf16x8*)&Lp[4096 + bi[j]];
            bl[j] = *(const bf16x8*)&Lp[8192 + bi[j]];
        }
#pragma unroll
        for (int i = 0; i < 4; i++) a[i] = *(const bf16x8*)&Lp[ai[i]];

        __builtin_amdgcn_s_setprio(1);
#pragma unroll
        for (int j = 0; j < 4; j++)
#pragma unroll
            for (int i = 0; i < 4; i++) { MM(i, j, a[i], bh[j], bl[j]) }
        __builtin_amdgcn_s_setprio(0);

        __builtin_amdgcn_s_barrier();
    }
#undef STAGE
#undef MM

    // epilogue: C/D frag layout col = lane&15, row = (lane>>4)*4 + reg
    float* Cp = (OUT_MODE == 1) ? (Cf + (size_t)bz * M * N) : Cf;
#pragma unroll
    for (int i = 0; i < 4; i++) {
        const int row = bm * 128 + wm * 64 + i * 16 + fq * 4;
#pragma unroll
        for (int j = 0; j < 4; j++) {
            const int col = bn * 128 + wn * 64 + j * 16 + fr;
            if (OUT_MODE == 0) {
                const float bb = bias[col];
#pragma unroll
                for (int rg = 0; rg < 4; rg++) {
                    size_t off = (size_t)(row + rg) * N + col;
                    float v = acc[i][j][rg] + bb;
                    if (RELU) v = fmaxf(v, 0.f);
                    Ch[off] = bfbits((__bf16)v);
                }
            } else {
#pragma unroll
                for (int rg = 0; rg < 4; rg++) {
                    size_t off = (size_t)(row + rg) * N + col;
                    Cp[off] = acc[i][j][rg];
                }
            }
        }
    }
}

// ---------------- fused LN2, wave-per-row: out = LN(y0+y1+x+b2) ----------------
__global__ __launch_bounds__(256) void k_ln2f(
    const float* __restrict__ y0, const float* __restrict__ y1,
    const float* __restrict__ x, const float* __restrict__ b2,
    const float* __restrict__ g, const float* __restrict__ b,
    float* __restrict__ out)
{
    const int t = threadIdx.x, lane = t & 63, w = t >> 6;
    const int row = blockIdx.x * 4 + w;
    const size_t base = (size_t)row * DM + lane * 12;

    float xs[12]; float sum = 0.f;
#pragma unroll
    for (int i = 0; i < 3; i++) {
        float4 a = ((const float4*)(y0 + base))[i];
        float4 bv = ((const float4*)(y1 + base))[i];
        float4 c = ((const float4*)(x + base))[i];
        float4 d = ((const float4*)(b2 + lane * 12))[i];
        xs[i*4+0] = a.x + bv.x + c.x + d.x;
        xs[i*4+1] = a.y + bv.y + c.y + d.y;
        xs[i*4+2] = a.z + bv.z + c.z + d.z;
        xs[i*4+3] = a.w + bv.w + c.w + d.w;
        sum += xs[i*4+0] + xs[i*4+1] + xs[i*4+2] + xs[i*4+3];
    }
    float mean = wred_sum(sum) * (1.f / DM);
    float vs = 0.f;
#pragma unroll
    for (int i = 0; i < 12; i++) { float dd = xs[i] - mean; vs += dd * dd; }
    float rstd = rsqrtf(wred_sum(vs) * (1.f / DM) + 1e-6f);
#pragma unroll
    for (int i = 0; i < 3; i++) {
        float4 gv = ((const float4*)(g + lane * 12))[i];
        float4 bb = ((const float4*)(b + lane * 12))[i];
        float4 o;
        o.x = (xs[i*4+0] - mean) * rstd * gv.x + bb.x;
        o.y = (xs[i*4+1] - mean) * rstd * gv.y + bb.y;
        o.z = (xs[i*4+2] - mean) * rstd * gv.z + bb.z;
        o.w = (xs[i*4+3] - mean) * rstd * gv.w + bb.w;
        ((float4*)(out + base))[i] = o;
    }
}

extern "C" void kernel_launch(void* const* d_in, const int* in_sizes, int n_in,
                              void* d_out, int out_size, void* d_ws, size_t ws_size,
                              hipStream_t stream) {
    const float* enc  = (const float*)d_in[0];
    const float* mask = (const float*)d_in[1];
    const float* wq = (const float*)d_in[2];  const float* bq = (const float*)d_in[3];
    const float* wk = (const float*)d_in[4];  const float* bk = (const float*)d_in[5];
    const float* wv = (const float*)d_in[6];  const float* bv = (const float*)d_in[7];
    const float* g1 = (const float*)d_in[8];  const float* be1 = (const float*)d_in[9];
    const float* w1 = (const float*)d_in[10]; const float* b1  = (const float*)d_in[11];
    const float* w2 = (const float*)d_in[12]; const float* b2  = (const float*)d_in[13];
    const float* g2 = (const float*)d_in[14]; const float* be2 = (const float*)d_in[15];
    float* out = (float*)d_out;

    // workspace layout (~157 MB)
    char* p = (char*)d_ws;
    float* x  = (float*)p;                 p += (size_t)ROWS * DM * 4;   // 25.2 MB
    float* y01 = (float*)p;                p += 2 * (size_t)ROWS * DM * 4; // 50.3 MB (2 partials)
    u16* xh = (u16*)p; p += (size_t)ROWS * DM * 2;                       // 12.6 MB
    u16* hh = (u16*)p; p += (size_t)ROWS * DI * 2;                       // 50.3 MB
    u16* w1h = (u16*)p; p += (size_t)DM * DI * 2;                        // 4.7 MB
    u16* w1l = (u16*)p; p += (size_t)DM * DI * 2;
    u16* w2h = (u16*)p; p += (size_t)DM * DI * 2;
    u16* w2l = (u16*)p; p += (size_t)DM * DI * 2;

    k_wprep<<<dim3(DI / 32, DM / 32), 256, 0, stream>>>(w1, w1h, w1l, DM, DI);
    k_wprep<<<dim3(DM / 32, DI / 32), 256, 0, stream>>>(w2, w2h, w2l, DI, DM);

    k_attn_ln1<<<ROWS / 4, 256, 0, stream>>>(enc, mask, wq, bq, wk, bk, wv, bv, g1, be1,
                                             x, xh);

    // GEMM1: h = relu(x @ w1 + b1) -> bf16  (M=8192, N=3072, K=768), grid 24x64=1536
    k_gemm4<1, 1, 0><<<dim3(DI / 128, ROWS / 128, 1), 256, 0, stream>>>(
        xh, w1h, w1l, b1, nullptr, hh, ROWS, DI, DM);

    // GEMM2: partial sums y0,y1 = h @ w2 per K-half (split-K=2, grid 6x64x2=768)
    k_gemm4<2, 0, 1><<<dim3(DM / 128, ROWS / 128, 2), 256, 0, stream>>>(
        hh, w2h, w2l, nullptr, y01, nullptr, ROWS, DM, DI);

    // out = LN(y0 + y1 + x + b2)
    k_ln2f<<<ROWS / 4, 256, 0, stream>>>(y01, y01 + (size_t)ROWS * DM, x, b2, g2, be2, out);
}

// Round 9
// 255.658 us; speedup vs baseline: 1.7949x; 1.2370x over previous
//
#include <hip/hip_runtime.h>

#define ROWS 8192
#define LW 96
#define HW 8
#define DM 768
#define DI 3072

typedef _Float16 f16;
typedef f16 f16x8 __attribute__((ext_vector_type(8)));
typedef float f32x4 __attribute__((ext_vector_type(4)));
typedef unsigned short u16;
typedef unsigned int u32;

__device__ __forceinline__ u16 f16bits(float v) {
    f16 h = (f16)v;
    return __builtin_bit_cast(u16, h);
}
__device__ __forceinline__ void gload16(const void* g, void* l) {
    __builtin_amdgcn_global_load_lds((const __attribute__((address_space(1))) unsigned int*)g,
                                     (__attribute__((address_space(3))) unsigned int*)l, 16, 0, 0);
}
__device__ __forceinline__ float wred_sum(float v) {
#pragma unroll
    for (int o = 32; o; o >>= 1) v += __shfl_xor(v, o);
    return v;
}
__device__ __forceinline__ float wred_max(float v) {
#pragma unroll
    for (int o = 32; o; o >>= 1) v = fmaxf(v, __shfl_xor(v, o));
    return v;
}

// ---------------- Kernel 0: weight transpose + f16 convert ----------------
// W[K][N] fp32 -> T[N][K] f16 bits
__global__ __launch_bounds__(256) void k_wprep(
    const float* __restrict__ W, u16* __restrict__ Th, int K, int N)
{
    __shared__ float tile[32][33];
    const int tx = threadIdx.x & 31, ty = threadIdx.x >> 5;
    const int k0 = blockIdx.y * 32, n0 = blockIdx.x * 32;
#pragma unroll
    for (int i = 0; i < 32; i += 8)
        tile[ty + i][tx] = W[(size_t)(k0 + ty + i) * N + n0 + tx];
    __syncthreads();
#pragma unroll
    for (int i = 0; i < 32; i += 8) {
        int n = n0 + ty + i, k = k0 + tx;
        Th[(size_t)n * K + k] = f16bits(tile[tx][ty + i]);
    }
}

// ---------------- Kernel 1: attention + residual + LN1, wave-per-row ----------------
// Zero __syncthreads: 4 independent waves/block, reductions via shfl_xor.
// mask is Toeplitz: mask[j,k] = g[95-j+k]. Lane owns windows lane and 64+lane.
__global__ __launch_bounds__(256) void k_attn_ln1(
    const float* __restrict__ inp, const float* __restrict__ mask,
    const float* __restrict__ wq, const float* __restrict__ bq,
    const float* __restrict__ wk, const float* __restrict__ bk,
    const float* __restrict__ wv, const float* __restrict__ bv,
    const float* __restrict__ g1, const float* __restrict__ be1,
    float* __restrict__ xout, u16* __restrict__ xh)
{
    const int t = threadIdx.x, lane = t & 63, w = t >> 6;
    const int row = blockIdx.x * 4 + w;
    __shared__ float kvS[4][96];
    __shared__ float gS[4][192];

    const float* rp = inp + (size_t)row * DM;

    float xr[8], xr2[8];
    {
        float4 a = ((const float4*)rp)[lane * 2];
        float4 b = ((const float4*)rp)[lane * 2 + 1];
        xr[0]=a.x; xr[1]=a.y; xr[2]=a.z; xr[3]=a.w;
        xr[4]=b.x; xr[5]=b.y; xr[6]=b.z; xr[7]=b.w;
    }
    if (lane < 32) {
        float4 a = ((const float4*)rp)[128 + lane * 2];
        float4 b = ((const float4*)rp)[128 + lane * 2 + 1];
        xr2[0]=a.x; xr2[1]=a.y; xr2[2]=a.z; xr2[3]=a.w;
        xr2[4]=b.x; xr2[5]=b.y; xr2[6]=b.z; xr2[7]=b.w;
    } else {
#pragma unroll
        for (int i = 0; i < 8; i++) xr2[i] = 0.f;
    }

    {
        int m1 = lane;
        gS[w][m1] = mask[95 * LW + m1];
        int m2 = 64 + lane;
        gS[w][m2] = (m2 < 96) ? mask[95 * LW + m2] : mask[(190 - m2) * LW + 95];
        int m3 = 128 + lane;
        if (m3 <= 190) gS[w][m3] = mask[(190 - m3) * LW + 95];
    }

    float q1, k1, v1, q2, k2, v2;
    {
        float aq = 0.f, ak = 0.f, av = 0.f, aq2 = 0.f, ak2 = 0.f, av2 = 0.f;
#pragma unroll
        for (int i = 0; i < 8; i++) {
            float wqi = wq[i], wki = wk[i], wvi = wv[i];
            aq = fmaf(xr[i],  wqi, aq);  ak = fmaf(xr[i],  wki, ak);  av = fmaf(xr[i],  wvi, av);
            aq2 = fmaf(xr2[i], wqi, aq2); ak2 = fmaf(xr2[i], wki, ak2); av2 = fmaf(xr2[i], wvi, av2);
        }
        q1 = aq + bq[0]; k1 = ak + bk[0]; v1 = av + bv[0];
        q2 = aq2 + bq[0]; k2 = ak2 + bk[0]; v2 = av2 + bv[0];
    }

    kvS[w][lane] = k1;
    if (lane < 32) kvS[w][64 + lane] = k2;
    asm volatile("s_waitcnt lgkmcnt(0)" ::: "memory");

    float nq2 = wred_sum(q1 * q1 + (lane < 32 ? q2 * q2 : 0.f));
    float nk2 = wred_sum(k1 * k1 + (lane < 32 ? k2 * k2 : 0.f));
    float inv = 1.f / fmaxf(sqrtf(nq2) * sqrtf(nk2), 1e-12f);

    float km1 = 0.f, km2 = 0.f;
    {
        const float* gw = gS[w];
        const float* kw = kvS[w];
        const int b1 = 95 - lane;
        const int b2 = (lane < 32) ? (31 - lane) : 0;
#pragma unroll 4
        for (int kk = 0; kk < 96; kk++) {
            float kv = kw[kk];
            km1 = fmaf(gw[b1 + kk], kv, km1);
            km2 = fmaf(gw[b2 + kk], kv, km2);
        }
    }

    float sc1 = q1 * km1 * inv;
    float sc2 = (lane < 32) ? (q2 * km2 * inv) : -1e30f;
    float mx = wred_max(fmaxf(sc1, sc2));
    float e1 = __expf(sc1 - mx);
    float e2 = (lane < 32) ? __expf(sc2 - mx) : 0.f;
    float se = wred_sum(e1 + e2);
    float r1 = (e1 / se) * v1;
    float r2 = (e2 / se) * v2;

    float xn[8], xn2[8];
    float sum = 0.f;
#pragma unroll
    for (int i = 0; i < 8; i++) { xn[i] = xr[i] + r1; sum += xn[i]; }
    if (lane < 32) {
#pragma unroll
        for (int i = 0; i < 8; i++) { xn2[i] = xr2[i] + r2; sum += xn2[i]; }
    }
    float mean = wred_sum(sum) * (1.f / DM);
    float vs = 0.f;
#pragma unroll
    for (int i = 0; i < 8; i++) { float d = xn[i] - mean; vs += d * d; }
    if (lane < 32) {
#pragma unroll
        for (int i = 0; i < 8; i++) { float d = xn2[i] - mean; vs += d * d; }
    }
    float rstd = rsqrtf(wred_sum(vs) * (1.f / DM) + 1e-6f);

    float* xo = xout + (size_t)row * DM;
    u16* xho = xh + (size_t)row * DM;
    {
        const int d0 = lane * 8;
        float4 ga = ((const float4*)(g1 + d0))[0], gb = ((const float4*)(g1 + d0))[1];
        float4 ba = ((const float4*)(be1 + d0))[0], bb = ((const float4*)(be1 + d0))[1];
        float o[8];
        o[0]=(xn[0]-mean)*rstd*ga.x+ba.x; o[1]=(xn[1]-mean)*rstd*ga.y+ba.y;
        o[2]=(xn[2]-mean)*rstd*ga.z+ba.z; o[3]=(xn[3]-mean)*rstd*ga.w+ba.w;
        o[4]=(xn[4]-mean)*rstd*gb.x+bb.x; o[5]=(xn[5]-mean)*rstd*gb.y+bb.y;
        o[6]=(xn[6]-mean)*rstd*gb.z+bb.z; o[7]=(xn[7]-mean)*rstd*gb.w+bb.w;
        ((float4*)(xo + d0))[0] = make_float4(o[0], o[1], o[2], o[3]);
        ((float4*)(xo + d0))[1] = make_float4(o[4], o[5], o[6], o[7]);
        uint4 pk;
        pk.x = (u32)f16bits(o[0]) | ((u32)f16bits(o[1]) << 16);
        pk.y = (u32)f16bits(o[2]) | ((u32)f16bits(o[3]) << 16);
        pk.z = (u32)f16bits(o[4]) | ((u32)f16bits(o[5]) << 16);
        pk.w = (u32)f16bits(o[6]) | ((u32)f16bits(o[7]) << 16);
        *(uint4*)(xho + d0) = pk;
    }
    if (lane < 32) {
        const int d0 = 512 + lane * 8;
        float4 ga = ((const float4*)(g1 + d0))[0], gb = ((const float4*)(g1 + d0))[1];
        float4 ba = ((const float4*)(be1 + d0))[0], bb = ((const float4*)(be1 + d0))[1];
        float o[8];
        o[0]=(xn2[0]-mean)*rstd*ga.x+ba.x; o[1]=(xn2[1]-mean)*rstd*ga.y+ba.y;
        o[2]=(xn2[2]-mean)*rstd*ga.z+ba.z; o[3]=(xn2[3]-mean)*rstd*ga.w+ba.w;
        o[4]=(xn2[4]-mean)*rstd*gb.x+bb.x; o[5]=(xn2[5]-mean)*rstd*gb.y+bb.y;
        o[6]=(xn2[6]-mean)*rstd*gb.z+bb.z; o[7]=(xn2[7]-mean)*rstd*gb.w+bb.w;
        ((float4*)(xo + d0))[0] = make_float4(o[0], o[1], o[2], o[3]);
        ((float4*)(xo + d0))[1] = make_float4(o[4], o[5], o[6], o[7]);
        uint4 pk;
        pk.x = (u32)f16bits(o[0]) | ((u32)f16bits(o[1]) << 16);
        pk.y = (u32)f16bits(o[2]) | ((u32)f16bits(o[3]) << 16);
        pk.z = (u32)f16bits(o[4]) | ((u32)f16bits(o[5]) << 16);
        pk.w = (u32)f16bits(o[6]) | ((u32)f16bits(o[7]) << 16);
        *(uint4*)(xho + d0) = pk;
    }
}

// ---------------- 4-wave f16 MFMA GEMM, 128x128 tile, BK=32 ----------------
// C = op(A @ B + bias) fp32-accumulated from f16 operands. A (M x K) f16
// row-major; B pre-transposed (N x K) f16. Ring-2 LDS of 16KB slots (32 KB
// total -> 5 blocks/CU by LDS), 2-barrier loop, counted vmcnt(4) (never 0
// mid-loop), XCD-swizzled. Per-slot u16 layout: A [0,4096) B [4096,8192).
// BMFAST=1: bm iterates fastest within an XCD chunk (keeps the B panel
// L2-resident -- for large-N GEMM1). BMFAST=0: bn fastest (GEMM2).
template<int SPLITK, int RELU, int OUT_MODE, int BMFAST>
__global__ __launch_bounds__(256, 4) void k_gemm4(
    const u16* __restrict__ Ah, const u16* __restrict__ Bh,
    const float* __restrict__ bias, float* __restrict__ Cf,
    u16* __restrict__ Ch, int M, int N, int K)
{
    __shared__ u16 S[2 * 8192];   // 32 KB

    const int t = threadIdx.x;
    const int lane = t & 63, w = t >> 6;
    const int wm = w >> 1, wn = w & 1;          // 2 M-waves x 2 N-waves
    const int fr = lane & 15, fq = lane >> 4;

    // bijective XCD swizzle on the flat block index (grid size % 8 == 0)
    const int gn = gridDim.x, gm = gridDim.y;
    int Lidx = blockIdx.x + gn * (blockIdx.y + gm * blockIdx.z);
    const int nb = gn * gm * SPLITK;
    int sID = ((nb & 7) == 0) ? ((Lidx & 7) * (nb >> 3) + (Lidx >> 3)) : Lidx;
    const int bz = sID / (gn * gm);
    const int rr = sID - bz * (gn * gm);
    int bm, bn;
    if (BMFAST) { bm = rr % gm; bn = rr / gm; }
    else        { bm = rr / gn; bn = rr - (rr / gn) * gn; }

    const int KS = K / SPLITK;
    const int NT = KS / 32;
    const int kb = bz * KS;

    // staging (verified r2/r4 math): chunk s -> row r=s>>2, lds chunk c'=s&3,
    // source chunk c = c' ^ ((r>>1)&3); +64-row offset keeps (r>>1)&3.
    const int r0 = t >> 2;                       // 0..63
    const int c0 = (t & 3) ^ ((r0 >> 1) & 3);
    const size_t aoff  = (size_t)(bm * 128 + r0) * K + kb + c0 * 8;
    const size_t aoff2 = aoff + (size_t)64 * K;
    const size_t boff  = (size_t)(bn * 128 + r0) * K + kb + c0 * 8;
    const size_t boff2 = boff + (size_t)64 * K;
    const int w512 = w * 512;                    // wave-uniform u16 offset

    f32x4 acc[4][4];
#pragma unroll
    for (int i = 0; i < 4; i++)
#pragma unroll
        for (int j = 0; j < 4; j++) acc[i][j] = (f32x4)0.f;

    // frag-read LDS indices (u16 units), loop-invariant; <=2-way bank alias (free)
    int ai[4], bi[4];
#pragma unroll
    for (int i = 0; i < 4; i++) { int rA = wm * 64 + i * 16 + fr; ai[i] = rA * 32 + (fq ^ ((rA >> 1) & 3)) * 8; }
#pragma unroll
    for (int j = 0; j < 4; j++) { int rB = wn * 64 + j * 16 + fr; bi[j] = rB * 32 + (fq ^ ((rB >> 1) & 3)) * 8; }

#define STAGE(tile, bb)                                                  \
    { u16* Lb = S + (bb) * 8192 + w512;                                  \
      const size_t kk = (size_t)(tile) * 32;                             \
      gload16(Ah + aoff  + kk, Lb + 0);                                  \
      gload16(Ah + aoff2 + kk, Lb + 2048);                               \
      gload16(Bh + boff  + kk, Lb + 4096);                               \
      gload16(Bh + boff2 + kk, Lb + 6144); }

    STAGE(0, 0);

    for (int tt = 0; tt < NT; ++tt) {
        // stage next tile into the other slot, then certify tile tt landed:
        // own-wave counted vmcnt BEFORE barrier (r4-verified ordering).
        if (tt + 1 < NT) {
            STAGE(tt + 1, (tt + 1) & 1);
            asm volatile("s_waitcnt vmcnt(4)" ::: "memory");
        } else {
            asm volatile("s_waitcnt vmcnt(0)" ::: "memory");
        }
        __builtin_amdgcn_s_barrier();

        const u16* Lp = S + (tt & 1) * 8192;
        f16x8 a[4], b[4];
#pragma unroll
        for (int j = 0; j < 4; j++) b[j] = *(const f16x8*)&Lp[4096 + bi[j]];
#pragma unroll
        for (int i = 0; i < 4; i++) a[i] = *(const f16x8*)&Lp[ai[i]];

        __builtin_amdgcn_s_setprio(1);
#pragma unroll
        for (int j = 0; j < 4; j++)
#pragma unroll
            for (int i = 0; i < 4; i++)
                acc[i][j] = __builtin_amdgcn_mfma_f32_16x16x32_f16(a[i], b[j], acc[i][j], 0, 0, 0);
        __builtin_amdgcn_s_setprio(0);

        // WAR fence: next STAGE overwrites this slot only after all waves read it.
        __builtin_amdgcn_s_barrier();
    }
#undef STAGE

    // epilogue: C/D frag layout col = lane&15, row = (lane>>4)*4 + reg
    float* Cp = (OUT_MODE == 1) ? (Cf + (size_t)bz * M * N) : Cf;
#pragma unroll
    for (int i = 0; i < 4; i++) {
        const int row = bm * 128 + wm * 64 + i * 16 + fq * 4;
#pragma unroll
        for (int j = 0; j < 4; j++) {
            const int col = bn * 128 + wn * 64 + j * 16 + fr;
            if (OUT_MODE == 0) {
                const float bb = bias[col];
#pragma unroll
                for (int rg = 0; rg < 4; rg++) {
                    size_t off = (size_t)(row + rg) * N + col;
                    float v = acc[i][j][rg] + bb;
                    if (RELU) v = fmaxf(v, 0.f);
                    Ch[off] = f16bits(v);
                }
            } else {
#pragma unroll
                for (int rg = 0; rg < 4; rg++) {
                    size_t off = (size_t)(row + rg) * N + col;
                    Cp[off] = acc[i][j][rg];
                }
            }
        }
    }
}

// ---------------- fused LN2, wave-per-row: out = LN(y0+y1+x+b2) ----------------
__global__ __launch_bounds__(256) void k_ln2f(
    const float* __restrict__ y0, const float* __restrict__ y1,
    const float* __restrict__ x, const float* __restrict__ b2,
    const float* __restrict__ g, const float* __restrict__ b,
    float* __restrict__ out)
{
    const int t = threadIdx.x, lane = t & 63, w = t >> 6;
    const int row = blockIdx.x * 4 + w;
    const size_t base = (size_t)row * DM + lane * 12;

    float xs[12]; float sum = 0.f;
#pragma unroll
    for (int i = 0; i < 3; i++) {
        float4 a = ((const float4*)(y0 + base))[i];
        float4 bv = ((const float4*)(y1 + base))[i];
        float4 c = ((const float4*)(x + base))[i];
        float4 d = ((const float4*)(b2 + lane * 12))[i];
        xs[i*4+0] = a.x + bv.x + c.x + d.x;
        xs[i*4+1] = a.y + bv.y + c.y + d.y;
        xs[i*4+2] = a.z + bv.z + c.z + d.z;
        xs[i*4+3] = a.w + bv.w + c.w + d.w;
        sum += xs[i*4+0] + xs[i*4+1] + xs[i*4+2] + xs[i*4+3];
    }
    float mean = wred_sum(sum) * (1.f / DM);
    float vs = 0.f;
#pragma unroll
    for (int i = 0; i < 12; i++) { float dd = xs[i] - mean; vs += dd * dd; }
    float rstd = rsqrtf(wred_sum(vs) * (1.f / DM) + 1e-6f);
#pragma unroll
    for (int i = 0; i < 3; i++) {
        float4 gv = ((const float4*)(g + lane * 12))[i];
        float4 bb = ((const float4*)(b + lane * 12))[i];
        float4 o;
        o.x = (xs[i*4+0] - mean) * rstd * gv.x + bb.x;
        o.y = (xs[i*4+1] - mean) * rstd * gv.y + bb.y;
        o.z = (xs[i*4+2] - mean) * rstd * gv.z + bb.z;
        o.w = (xs[i*4+3] - mean) * rstd * gv.w + bb.w;
        ((float4*)(out + base))[i] = o;
    }
}

extern "C" void kernel_launch(void* const* d_in, const int* in_sizes, int n_in,
                              void* d_out, int out_size, void* d_ws, size_t ws_size,
                              hipStream_t stream) {
    const float* enc  = (const float*)d_in[0];
    const float* mask = (const float*)d_in[1];
    const float* wq = (const float*)d_in[2];  const float* bq = (const float*)d_in[3];
    const float* wk = (const float*)d_in[4];  const float* bk = (const float*)d_in[5];
    const float* wv = (const float*)d_in[6];  const float* bv = (const float*)d_in[7];
    const float* g1 = (const float*)d_in[8];  const float* be1 = (const float*)d_in[9];
    const float* w1 = (const float*)d_in[10]; const float* b1  = (const float*)d_in[11];
    const float* w2 = (const float*)d_in[12]; const float* b2  = (const float*)d_in[13];
    const float* g2 = (const float*)d_in[14]; const float* be2 = (const float*)d_in[15];
    float* out = (float*)d_out;

    // workspace layout (~148 MB)
    char* p = (char*)d_ws;
    float* x  = (float*)p;                 p += (size_t)ROWS * DM * 4;     // 25.2 MB
    float* y01 = (float*)p;                p += 2 * (size_t)ROWS * DM * 4; // 50.3 MB (2 partials)
    u16* xh = (u16*)p; p += (size_t)ROWS * DM * 2;                         // 12.6 MB
    u16* hh = (u16*)p; p += (size_t)ROWS * DI * 2;                         // 50.3 MB
    u16* w1h = (u16*)p; p += (size_t)DM * DI * 2;                          // 4.7 MB
    u16* w2h = (u16*)p; p += (size_t)DM * DI * 2;                          // 4.7 MB

    k_wprep<<<dim3(DI / 32, DM / 32), 256, 0, stream>>>(w1, w1h, DM, DI);
    k_wprep<<<dim3(DM / 32, DI / 32), 256, 0, stream>>>(w2, w2h, DI, DM);

    k_attn_ln1<<<ROWS / 4, 256, 0, stream>>>(enc, mask, wq, bq, wk, bk, wv, bv, g1, be1,
                                             x, xh);

    // GEMM1: h = relu(x @ w1 + b1) -> f16  (M=8192, N=3072, K=768), grid 24x64=1536
    // BMFAST=1: B panel (0.56 MB/XCD-chunk) stays L2-resident.
    k_gemm4<1, 1, 0, 1><<<dim3(DI / 128, ROWS / 128, 1), 256, 0, stream>>>(
        xh, w1h, b1, nullptr, hh, ROWS, DI, DM);

    // GEMM2: partial sums y0,y1 = h @ w2 per K-half (split-K=2, grid 6x64x2=768)
    k_gemm4<2, 0, 1, 0><<<dim3(DM / 128, ROWS / 128, 2), 256, 0, stream>>>(
        hh, w2h, nullptr, y01, nullptr, ROWS, DM, DI);

    // out = LN(y0 + y1 + x + b2)
    k_ln2f<<<ROWS / 4, 256, 0, stream>>>(y01, y01 + (size_t)ROWS * DM, x, b2, g2, be2, out);
}